// Round 16
// baseline (790.654 us; speedup 1.0000x reference)
//
#include <hip/hip_runtime.h>
#include <math.h>

#define BATCH 8
#define NPTS 4096
#define SSAMP 256
#define KNBR 128
#define GGRID 2025

typedef __attribute__((ext_vector_type(8))) short bf16x8;
typedef __attribute__((ext_vector_type(8))) unsigned short u16x8;
typedef __attribute__((ext_vector_type(4))) float f32x4;
#define MFMA16(a, b, c) __builtin_amdgcn_mfma_f32_16x16x32_bf16((a), (b), (c), 0, 0, 0)

__device__ __forceinline__ float lrelu01(float v) { return v > 0.f ? v : 0.01f * v; }
__device__ __forceinline__ unsigned short f2bf(float f) {
    unsigned u = __float_as_uint(f);
    unsigned r = (u + 0x7FFFu + ((u >> 16) & 1u)) >> 16;
    return (unsigned short)r;
}
__device__ __forceinline__ unsigned long long umax64(unsigned long long a, unsigned long long b) {
    return a > b ? a : b;
}
__device__ __forceinline__ void spin_ge(const int* p, int target) {
    while (__hip_atomic_load(p, __ATOMIC_RELAXED, __HIP_MEMORY_SCOPE_AGENT) < target)
        __builtin_amdgcn_s_sleep(16);
}
__device__ __forceinline__ float aload(const float* p) {
    return __hip_atomic_load((float*)p, __ATOMIC_RELAXED, __HIP_MEMORY_SCOPE_AGENT);
}
__device__ __forceinline__ void astore(float* p, float v) {
    __hip_atomic_store(p, v, __ATOMIC_RELAXED, __HIP_MEMORY_SCOPE_AGENT);
}

// Topological block order (every wait targets a lower block index):
//  [0,8)        fps                      -> prog[b] (atomics, no fence)
//  [8,959)      preconv                  -> cnts[19]=39(W123) [147]=144(We1T) [148]=512(We2T) [149]=256(WfT)
//  [959,1983)   pc s<128  (cons=blk-959) -> cnts[150+rb]   (rb even)
//  [1983,2015)  e1 even rb               -> cnts[rb]
//  [2015,2143)  e2v even rb              -> cnts[16]
//  [2143,3167)  pc s>=128 (cons=1024+blk-2143)             (rb odd)
//  [3167,3199)  e1 odd rb
//  [3199,3327)  e2v odd rb
//  [3327,3343)  ukern                    -> cnts[17]/[18]
//  [3343,3851)  ff1 (j,cc)               -> pts atomics, cnts[20+j]
//  [3851,4359)  ff2 (j,cc)               -> out atomics
__global__ void __launch_bounds__(256, 3) mega_kernel(
    const float* __restrict__ pos, float* __restrict__ newpos, int* __restrict__ prog,
    int* __restrict__ cnts,
    const float* __restrict__ Wt, const float* __restrict__ bt,
    const float* __restrict__ Wc1, const float* __restrict__ Wc2, const float* __restrict__ Wc3,
    const float* __restrict__ We1, const float* __restrict__ We2,
    const float* __restrict__ Wf12, const float* __restrict__ Wf22,
    unsigned short* __restrict__ W1T, unsigned short* __restrict__ W2T,
    unsigned short* __restrict__ W3T, unsigned short* __restrict__ We1T,
    unsigned short* __restrict__ We2T, unsigned short* __restrict__ Wf12T,
    unsigned short* __restrict__ Wf22T,
    const float* __restrict__ bc1, const float* __restrict__ bc2, const float* __restrict__ bc3,
    unsigned short* __restrict__ encin,
    const float* __restrict__ be1, unsigned short* __restrict__ e1h,
    const float* __restrict__ be2, float* __restrict__ zacc,
    const float* __restrict__ Wf11, const float* __restrict__ bf11,
    const float* __restrict__ Wf21, const float* __restrict__ bf21,
    float* __restrict__ u1, float* __restrict__ u2,
    const float* __restrict__ bf12, const float* __restrict__ Wf13, const float* __restrict__ bf13,
    const float* __restrict__ bf22, const float* __restrict__ Wf23, const float* __restrict__ bf23,
    float* __restrict__ pts, float* __restrict__ outv) {
    __shared__ __align__(16) unsigned char smem[53760];
    int blk = blockIdx.x, t = threadIdx.x;
    int wave = t >> 6, lane = t & 63;
    int quad = lane >> 4, l16 = lane & 15;

    if (blk < 8) {
        // ================= FPS producer (R14: no fences, delayed release) =================
        float* pxs = (float*)smem;
        float* pys = (float*)(smem + 16384);
        float* pzs = (float*)(smem + 32768);
        float* npb = (float*)(smem + 49152);
        unsigned long long* rk = (unsigned long long*)(smem + 52224);
        int b = blk;
        const float* P = pos + (size_t)b * NPTS * 3;
        float* np = newpos + (size_t)b * SSAMP * 3;
        float px[16], py[16], pz[16], mind[16];
#pragma unroll
        for (int j = 0; j < 16; ++j) {
            int n = t + 256 * j;
            float X = P[n * 3 + 0], Y = P[n * 3 + 1], Z = P[n * 3 + 2];
            px[j] = X; py[j] = Y; pz[j] = Z;
            pxs[n] = X; pys[n] = Y; pzs[n] = Z;
            mind[j] = 3.402823466e+38f;
        }
        float cx = P[0], cy = P[1], cz = P[2];
        if (t == 0) { npb[0] = cx; npb[1] = cy; npb[2] = cz; }
        __syncthreads();
        for (int s = 1; s < SSAMP; ++s) {
            int p = s & 1;
            unsigned long long k[16];
#pragma unroll
            for (int j = 0; j < 16; ++j) {
                float dx = __fsub_rn(px[j], cx), dy = __fsub_rn(py[j], cy), dz = __fsub_rn(pz[j], cz);
                float d = __fadd_rn(__fadd_rn(__fmul_rn(dx, dx), __fmul_rn(dy, dy)), __fmul_rn(dz, dz));
                mind[j] = fminf(mind[j], d);
                k[j] = ((unsigned long long)__float_as_uint(mind[j]) << 32)
                     | (unsigned)~(unsigned)(t + 256 * j);
            }
#pragma unroll
            for (int st = 8; st > 0; st >>= 1)
#pragma unroll
                for (int j = 0; j < st; ++j) k[j] = umax64(k[j], k[j + st]);
            unsigned long long key = k[0];
            {
                unsigned long long a = __shfl_xor(key, 1, 64);
                unsigned long long b2 = __shfl_xor(key, 2, 64);
                unsigned long long c = __shfl_xor(key, 3, 64);
                key = umax64(umax64(key, a), umax64(b2, c));
                a = __shfl_xor(key, 4, 64);
                b2 = __shfl_xor(key, 8, 64);
                c = __shfl_xor(key, 12, 64);
                key = umax64(umax64(key, a), umax64(b2, c));
                a = __shfl_xor(key, 16, 64);
                b2 = __shfl_xor(key, 32, 64);
                c = __shfl_xor(key, 48, 64);
                key = umax64(umax64(key, a), umax64(b2, c));
            }
            if (lane == 0) rk[p * 4 + wave] = key;
            __syncthreads();
            unsigned long long k0 = rk[p * 4 + 0], k1 = rk[p * 4 + 1];
            unsigned long long k2 = rk[p * 4 + 2], k3 = rk[p * 4 + 3];
            unsigned long long bk = umax64(umax64(k0, k1), umax64(k2, k3));
            int nx = (int)(~(unsigned)(bk & 0xFFFFFFFFull));
            cx = pxs[nx]; cy = pys[nx]; cz = pzs[nx];
            if (t == 0) {
                npb[s * 3 + 0] = cx;
                npb[s * 3 + 1] = cy;
                npb[s * 3 + 2] = cz;
            }
            if ((s & 7) == 7) {
                if (t < 24) astore(&np[(s - 7) * 3 + t], npb[(s - 7) * 3 + t]);
                if (t == 0 && s >= 15)
                    __hip_atomic_store(&prog[b], s - 8, __ATOMIC_RELAXED, __HIP_MEMORY_SCOPE_AGENT);
            }
        }
        __syncthreads();
        if (t == 0)
            __hip_atomic_store(&prog[b], 255, __ATOMIC_RELAXED, __HIP_MEMORY_SCOPE_AGENT);
        return;
    }

    if (blk < 959) {
        // ================= preconv =================
        int pb = blk - 8;
        const int S1 = 6144, S2 = 8192, S3 = 65536, S4 = 294912, S5 = 1048576, S6 = 262144;
#pragma unroll
        for (int j = 0; j < 8; ++j) {
            int o = pb * 2048 + t + j * 256;
            int q = o;
            if (q < S1) { int n = q / 96, k = q - n * 96; W1T[q] = f2bf(k < 67 ? Wc1[k * 64 + n] : 0.f); continue; }
            q -= S1;
            if (q < S2) { int n = q >> 6, k = q & 63; W2T[q] = f2bf(Wc2[k * 128 + n]); continue; }
            q -= S2;
            if (q < S3) { int n = q >> 7, k = q & 127; W3T[q] = f2bf(Wc3[k * 512 + n]); continue; }
            q -= S3;
            if (q < S4) { int n = q / 576, k = q - n * 576; We1T[q] = f2bf(k < 515 ? We1[k * 512 + n] : 0.f); continue; }
            q -= S4;
            if (q < S5) {
                int np2 = q >> 9, k = q & 511;
                int src = (np2 & 1) ? 1024 + (np2 >> 1) : (np2 >> 1);
                We2T[q] = f2bf(We2[(size_t)k * 2048 + src]);
                continue;
            }
            q -= S5;
            if (q < S6) { int n = q >> 9, k = q & 511; Wf12T[q] = f2bf(Wf12[k * 512 + n]); continue; }
            q -= S6;
            { int n = q >> 9, k = q & 511; Wf22T[q] = f2bf(Wf22[k * 512 + n]); }
        }
        __syncthreads();
        if (t == 0) {
            __threadfence();   // bulk normal stores -> wb before release
            int ci = (pb < 39) ? 19 : (pb < 183) ? 147 : (pb < 695) ? 148 : 149;
            atomicAdd(&cnts[ci], 1);
        }
        return;
    }

    bool isPCa = blk < 1983;
    bool isPCb = (blk >= 2143 && blk < 3167);
    if (isPCa || isPCb) {
        // ================= pointconv consumer =================
        unsigned short* featl = (unsigned short*)smem;
        unsigned short* h2    = (unsigned short*)smem;
        unsigned short* h1    = (unsigned short*)(smem + 34816);
        float* mred = (float*)(smem + 34816);
        int*   vld  = (int*)(smem + 53248);
        int*   wl   = (int*)smem;
        int*   cnt  = (int*)(smem + 2048);
        float* wtb  = (float*)(smem + 26624);

        int cons = isPCa ? (blk - 959) : (1024 + blk - 2143);
        int s = cons >> 3, b = cons & 7;
        int bs = b * 256 + s;

        if (t == 0) {
            spin_ge(&prog[b], s);
            spin_ge(&cnts[19], 39);
        }
        __syncthreads();
        __threadfence();   // acquire: W1T/W2T/W3T written via normal stores
        float q0 = aload(&newpos[(size_t)bs * 3 + 0]);
        float q1 = aload(&newpos[(size_t)bs * 3 + 1]);
        float q2 = aload(&newpos[(size_t)bs * 3 + 2]);

        const float* P = pos + (size_t)b * NPTS * 3;
        {
            int base = 0;
            for (int c = 0; c < 16 && base < KNBR; ++c) {
                int n = wave * 1024 + c * 64 + lane;
                float dx = __fsub_rn(P[n * 3 + 0], q0);
                float dy = __fsub_rn(P[n * 3 + 1], q1);
                float dz = __fsub_rn(P[n * 3 + 2], q2);
                float d2 = __fadd_rn(__fadd_rn(__fmul_rn(dx, dx), __fmul_rn(dy, dy)), __fmul_rn(dz, dz));
                bool in = (d2 <= 0.04f);
                unsigned long long mask = __ballot(in);
                if (in) {
                    int p = base + __popcll(mask & ((1ull << lane) - 1ull));
                    if (p < KNBR) wl[wave * 128 + p] = n;
                }
                base += __popcll(mask);
            }
            if (lane == 0) cnt[wave] = base < KNBR ? base : KNBR;
        }
        __syncthreads();
        {
            int c0 = cnt[0], c1 = cnt[1], c2 = cnt[2], c3 = cnt[3];
            if (t < 128) {
                int idx = -1, r = t;
                if (r < c0) idx = wl[r];
                else {
                    r -= c0;
                    if (r < c1) idx = wl[128 + r];
                    else {
                        r -= c1;
                        if (r < c2) idx = wl[256 + r];
                        else { r -= c2; if (r < c3) idx = wl[384 + r]; }
                    }
                }
                vld[t] = idx;
            }
            if (t < 192) wtb[t] = Wt[t];
            else wtb[t] = bt[t - 192];
        }
        __syncthreads();

        int vbits = 0;
#pragma unroll
        for (int i = 0; i < 2; ++i)
#pragma unroll
            for (int reg = 0; reg < 4; ++reg)
                if (vld[(2 * wave + i) * 16 + quad * 4 + reg] >= 0) vbits |= 1 << (i * 4 + reg);

        {
            int sr = t >> 1, sh = t & 1;
            int n = vld[sr];
            int ns = n < 0 ? 0 : n;
            const float* pp = pos + ((size_t)b * NPTS + ns) * 3;
            float p0 = pp[0], p1 = pp[1], p2 = pp[2];
            unsigned short* frow = &featl[sr * 104];
            u16x8 z8 = {0, 0, 0, 0, 0, 0, 0, 0};
            if (n >= 0) {
#pragma unroll
                for (int g = 0; g < 4; ++g) {
                    u16x8 v8;
#pragma unroll
                    for (int e = 0; e < 8; ++e) {
                        int c = sh * 32 + g * 8 + e;
                        float v = fmaf(p2, wtb[128 + c], fmaf(p1, wtb[64 + c], fmaf(p0, wtb[c], wtb[192 + c])));
                        v8[e] = (unsigned short)f2bf(lrelu01(v));
                    }
                    *(u16x8*)&frow[sh * 32 + g * 8] = v8;
                }
            } else {
#pragma unroll
                for (int g = 0; g < 4; ++g) *(u16x8*)&frow[sh * 32 + g * 8] = z8;
            }
            if (sh == 1) {
                u16x8 dv = z8;
                if (n >= 0) {
                    dv[0] = (unsigned short)f2bf(__fsub_rn(p0, q0));
                    dv[1] = (unsigned short)f2bf(__fsub_rn(p1, q1));
                    dv[2] = (unsigned short)f2bf(__fsub_rn(p2, q2));
                }
                *(u16x8*)&frow[64] = dv;
                *(u16x8*)&frow[72] = z8;
                *(u16x8*)&frow[80] = z8;
                *(u16x8*)&frow[88] = z8;
            }
        }
        __syncthreads();

        {
            f32x4 acc[2][4];
#pragma unroll
            for (int i = 0; i < 2; ++i)
#pragma unroll
                for (int nt = 0; nt < 4; ++nt) acc[i][nt] = (f32x4){0.f, 0.f, 0.f, 0.f};
#pragma unroll
            for (int ks = 0; ks < 3; ++ks) {
                bf16x8 afr[2];
#pragma unroll
                for (int i = 0; i < 2; ++i)
                    afr[i] = *(const bf16x8*)&featl[((2 * wave + i) * 16 + l16) * 104 + ks * 32 + quad * 8];
#pragma unroll
                for (int nt = 0; nt < 4; ++nt) {
                    bf16x8 bfr = *(const bf16x8*)(W1T + (nt * 16 + l16) * 96 + ks * 32 + quad * 8);
                    acc[0][nt] = MFMA16(afr[0], bfr, acc[0][nt]);
                    acc[1][nt] = MFMA16(afr[1], bfr, acc[1][nt]);
                }
            }
#pragma unroll
            for (int i = 0; i < 2; ++i)
#pragma unroll
                for (int nt = 0; nt < 4; ++nt) {
                    int col = nt * 16 + l16;
                    float bias = bc1[col];
#pragma unroll
                    for (int reg = 0; reg < 4; ++reg) {
                        int row = (2 * wave + i) * 16 + quad * 4 + reg;
                        h1[row * 72 + col] = f2bf(lrelu01(acc[i][nt][reg] + bias));
                    }
                }
        }
        __syncthreads();

        {
            f32x4 acc[2][8];
#pragma unroll
            for (int i = 0; i < 2; ++i)
#pragma unroll
                for (int nt = 0; nt < 8; ++nt) acc[i][nt] = (f32x4){0.f, 0.f, 0.f, 0.f};
#pragma unroll
            for (int ks = 0; ks < 2; ++ks) {
                bf16x8 afr[2];
#pragma unroll
                for (int i = 0; i < 2; ++i)
                    afr[i] = *(const bf16x8*)&h1[((2 * wave + i) * 16 + l16) * 72 + ks * 32 + quad * 8];
#pragma unroll
                for (int nt = 0; nt < 8; ++nt) {
                    bf16x8 bfr = *(const bf16x8*)(W2T + (nt * 16 + l16) * 64 + ks * 32 + quad * 8);
                    acc[0][nt] = MFMA16(afr[0], bfr, acc[0][nt]);
                    acc[1][nt] = MFMA16(afr[1], bfr, acc[1][nt]);
                }
            }
            __syncthreads();
#pragma unroll
            for (int i = 0; i < 2; ++i)
#pragma unroll
                for (int nt = 0; nt < 8; ++nt) {
                    int col = nt * 16 + l16;
                    float bias = bc2[col];
#pragma unroll
                    for (int reg = 0; reg < 4; ++reg) {
                        int row = (2 * wave + i) * 16 + quad * 4 + reg;
                        h2[row * 136 + col] = f2bf(lrelu01(acc[i][nt][reg] + bias));
                    }
                }
        }
        __syncthreads();

        for (int c3 = 0; c3 < 4; ++c3) {
            f32x4 acc[2][8];
#pragma unroll
            for (int i = 0; i < 2; ++i)
#pragma unroll
                for (int nt = 0; nt < 8; ++nt) acc[i][nt] = (f32x4){0.f, 0.f, 0.f, 0.f};
#pragma unroll
            for (int ks = 0; ks < 4; ++ks) {
                bf16x8 afr[2];
#pragma unroll
                for (int i = 0; i < 2; ++i)
                    afr[i] = *(const bf16x8*)&h2[((2 * wave + i) * 16 + l16) * 136 + ks * 32 + quad * 8];
#pragma unroll
                for (int nt = 0; nt < 8; ++nt) {
                    bf16x8 bfr = *(const bf16x8*)(W3T + ((size_t)((c3 * 8 + nt) * 16 + l16)) * 128 + ks * 32 + quad * 8);
                    acc[0][nt] = MFMA16(afr[0], bfr, acc[0][nt]);
                    acc[1][nt] = MFMA16(afr[1], bfr, acc[1][nt]);
                }
            }
#pragma unroll
            for (int nt = 0; nt < 8; ++nt) {
                float vmax = -3.402823466e+38f;
#pragma unroll
                for (int i = 0; i < 2; ++i)
#pragma unroll
                    for (int reg = 0; reg < 4; ++reg)
                        if (vbits & (1 << (i * 4 + reg))) vmax = fmaxf(vmax, acc[i][nt][reg]);
                vmax = fmaxf(vmax, __shfl_xor(vmax, 16));
                vmax = fmaxf(vmax, __shfl_xor(vmax, 32));
                if (lane < 16) mred[wave * 512 + (c3 * 8 + nt) * 16 + l16] = vmax;
            }
        }
        __syncthreads();
        unsigned short* erow = encin + (size_t)bs * 576;
        for (int c = t; c < 576; c += 256) {
            unsigned short v;
            if (c < 512) {
                float m4 = fmaxf(fmaxf(mred[c], mred[512 + c]), fmaxf(mred[1024 + c], mred[1536 + c]));
                v = f2bf(lrelu01(m4 + bc3[c]));
            } else if (c < 515) {
                v = f2bf(c == 512 ? q0 : (c == 513 ? q1 : q2));
            } else v = 0;
            erow[c] = v;
        }
        __syncthreads();
        if (t == 0) { __threadfence(); atomicAdd(&cnts[150 + (bs >> 7)], 1); }
        return;
    }

    bool isE1 = (blk >= 1983 && blk < 2015) || (blk >= 3167 && blk < 3199);
    bool isE2 = (blk >= 2015 && blk < 2143) || (blk >= 3199 && blk < 3327);
    if (isE1 || isE2) {
        // ================= e1 / e2v 128x128 MFMA GEMM =================
        unsigned short* As = (unsigned short*)smem;
        int rb, cb;
        const unsigned short* A;
        const unsigned short* BT;
        int Ka;
        if (isE1) {
            int j = (blk < 2015) ? (blk - 1983) : (blk - 3167);
            rb = 2 * (j >> 2) + (blk < 2015 ? 0 : 1);
            cb = j & 3;
            A = encin; BT = We1T; Ka = 576;
            if (t == 0) { spin_ge(&cnts[147], 144); spin_ge(&cnts[150 + rb], 128); }
        } else {
            int j = (blk < 2143) ? (blk - 2015) : (blk - 3199);
            rb = 2 * (j >> 4) + (blk < 2143 ? 0 : 1);
            cb = j & 15;
            A = e1h; BT = We2T; Ka = 512;
            if (t == 0) { spin_ge(&cnts[148], 512); spin_ge(&cnts[rb], 4); }
        }
        __syncthreads();
        __threadfence();   // acquire bulk normal-store data (encin/e1h + weights)
        int row0 = rb * 128, col0 = cb * 128;
        f32x4 acc[2][8];
#pragma unroll
        for (int i = 0; i < 2; ++i)
#pragma unroll
            for (int nt = 0; nt < 8; ++nt) acc[i][nt] = (f32x4){0.f, 0.f, 0.f, 0.f};
        int nk = Ka >> 6;
        int sr = t >> 1, sh = t & 1;
        const unsigned short* Arow = A + (size_t)(row0 + sr) * Ka + sh * 32;
        for (int ks = 0; ks < nk; ++ks) {
            u16x8 av[4];
#pragma unroll
            for (int j2 = 0; j2 < 4; ++j2) av[j2] = *(const u16x8*)(Arow + ks * 64 + j2 * 8);
            __syncthreads();
#pragma unroll
            for (int j2 = 0; j2 < 4; ++j2) *(u16x8*)&As[sr * 72 + sh * 32 + j2 * 8] = av[j2];
            __syncthreads();
#pragma unroll
            for (int ks2 = 0; ks2 < 2; ++ks2) {
                bf16x8 afr0 = *(const bf16x8*)&As[((2 * wave) * 16 + l16) * 72 + ks2 * 32 + quad * 8];
                bf16x8 afr1 = *(const bf16x8*)&As[((2 * wave + 1) * 16 + l16) * 72 + ks2 * 32 + quad * 8];
#pragma unroll
                for (int nt = 0; nt < 8; ++nt) {
                    bf16x8 bfr = *(const bf16x8*)(BT + (size_t)(col0 + nt * 16 + l16) * Ka + ks * 64 + ks2 * 32 + quad * 8);
                    acc[0][nt] = MFMA16(afr0, bfr, acc[0][nt]);
                    acc[1][nt] = MFMA16(afr1, bfr, acc[1][nt]);
                }
            }
        }
        if (isE1) {
#pragma unroll
            for (int i = 0; i < 2; ++i)
#pragma unroll
                for (int nt = 0; nt < 8; ++nt) {
                    int col = col0 + nt * 16 + l16;
                    float bv = be1[col];
#pragma unroll
                    for (int reg = 0; reg < 4; ++reg) {
                        int row = row0 + (2 * wave + i) * 16 + quad * 4 + reg;
                        e1h[(size_t)row * 512 + col] = f2bf(lrelu01(acc[i][nt][reg] + bv));
                    }
                }
            __syncthreads();
            if (t == 0) { __threadfence(); atomicAdd(&cnts[rb], 1); }
        } else {
            int b = row0 >> 8;
#pragma unroll
            for (int nt = 0; nt < 8; ++nt) {
                int colp = col0 + nt * 16 + l16;
                int c2 = colp >> 1;
                int srcc = (colp & 1) ? 1024 + c2 : c2;
                float bv = be2[srcc];
                float num = 0.f, den = 0.f;
#pragma unroll
                for (int i = 0; i < 2; ++i)
#pragma unroll
                    for (int reg = 0; reg < 4; ++reg) {
                        float val = acc[i][nt][reg] + bv;
                        float par = __shfl_xor(val, 1, 64);
                        float d = expf(-0.5f * par);
                        num += val * d;
                        den += d;
                    }
                num += __shfl_xor(num, 16, 64); den += __shfl_xor(den, 16, 64);
                num += __shfl_xor(num, 32, 64); den += __shfl_xor(den, 32, 64);
                if (quad == 0 && !(l16 & 1)) {
                    atomicAdd(&zacc[((b << 10) + c2) * 2 + 0], num);
                    atomicAdd(&zacc[((b << 10) + c2) * 2 + 1], den);
                }
            }
            __syncthreads();
            if (t == 0) atomicAdd(&cnts[16], 1);   // data via atomics: no fence
        }
        return;
    }

    if (blk < 3343) {
        // ================= ukern =================
        float* zt = (float*)smem;
        float* red = (float*)(smem + 32768);
        int j = blk - 3327;
        int dec = j >> 3, cb = j & 7;
        const float* W = dec ? Wf21 : Wf11;
        const float* bias = dec ? bf21 : bf11;
        float* u = dec ? u2 : u1;
        if (t == 0) spin_ge(&cnts[16], 256);
        __syncthreads();
#pragma unroll
        for (int i = 0; i < 32; ++i) {
            int o = t + i * 256;
            float num = aload(&zacc[o * 2 + 0]);
            float den = aload(&zacc[o * 2 + 1]);
            zt[(o & 1023) * 8 + (o >> 10)] = num / den;
        }
        __syncthreads();
        int c64 = t & 63, kc = t >> 6;
        int co = cb * 64 + c64;
        float acc[8];
#pragma unroll
        for (int r = 0; r < 8; ++r) acc[r] = 0.f;
        for (int i = 0; i < 256; ++i) {
            int ci = kc * 256 + i;
            float w = W[(size_t)ci * 512 + co];
            const float4* zp = (const float4*)&zt[ci * 8];
            float4 z0 = zp[0], z1 = zp[1];
            acc[0] = fmaf(z0.x, w, acc[0]); acc[1] = fmaf(z0.y, w, acc[1]);
            acc[2] = fmaf(z0.z, w, acc[2]); acc[3] = fmaf(z0.w, w, acc[3]);
            acc[4] = fmaf(z1.x, w, acc[4]); acc[5] = fmaf(z1.y, w, acc[5]);
            acc[6] = fmaf(z1.z, w, acc[6]); acc[7] = fmaf(z1.w, w, acc[7]);
        }
#pragma unroll
        for (int r = 0; r < 8; ++r) red[(kc * 64 + c64) * 8 + r] = acc[r];
        __syncthreads();
        if (kc == 0) {
#pragma unroll
            for (int r = 0; r < 8; ++r) {
                float v = red[(0 * 64 + c64) * 8 + r] + red[(1 * 64 + c64) * 8 + r]
                        + red[(2 * 64 + c64) * 8 + r] + red[(3 * 64 + c64) * 8 + r] + bias[co];
                astore(&u[r * 512 + co], v);
            }
        }
        __syncthreads();
        if (t == 0) atomicAdd(&cnts[17 + dec], 1);
        return;
    }

    // ================= foldfuse (j,cc) =================
    {
        unsigned short* As = (unsigned short*)smem;
        float* sW = (float*)(smem + 18432);
        float* sU = (float*)(smem + 24576);
        float* sP = (float*)(smem + 28672);
        float* sB = (float*)(smem + 30208);
        float* sRC = (float*)(smem + 30720);
        int dec = blk < 3851 ? 0 : 1;
        int idx0 = blk - (dec ? 3851 : 3343);
        int j = idx0 >> 2, cc = idx0 & 3;
        const float* u = dec ? u2 : u1;
        const float* Wfold = dec ? Wf21 : Wf11;
        int nExtra = dec ? 3 : 2;
        const unsigned short* WT = dec ? Wf22T : Wf12T;
        const float* bmid = dec ? bf22 : bf12;
        const float* wout = dec ? Wf23 : Wf13;
        const float* bout = dec ? bf23 : bf13;
        float* ov = dec ? outv : pts;
        int row0 = j * 128, col0 = cc * 128;
        int b0 = row0 / 2025;

        if (t == 0) {
            spin_ge(&cnts[149], 256);
            spin_ge(&cnts[17 + dec], 8);
            if (dec) spin_ge(&cnts[20 + j], 4);
        }
        __syncthreads();
        __threadfence();   // acquire WfT (preconv normal stores)

        for (int idx = t; idx < 1536; idx += 256) {
            int r = idx >> 9, c = idx & 511;
            sW[r * 512 + c] = (r < nExtra) ? Wfold[(size_t)(1024 + r) * 512 + c] : 0.f;
        }
        for (int idx = t; idx < 1024; idx += 256) {
            int rb = idx >> 9;
            int bb = b0 + rb; if (bb > 7) bb = 7;
            sU[rb * 512 + (idx & 511)] = aload(&u[bb * 512 + (idx & 511)]);
        }
        for (int idx = t; idx < 384; idx += 256) sP[idx] = wout[col0 * 3 + idx];
        if (t < 128) sB[t] = bmid[col0 + t];
        if (t < 128) {
            int rg = row0 + t; if (rg > 16199) rg = 16199;
            int b = rg / 2025, g = rg - b * 2025;
            if (dec == 0) {
                int i = g / 45, jj = g - i * 45;
                sRC[t * 4 + 0] = (jj == 44) ? 0.3f : (float)(-0.3 + jj * (0.6 / 44.0));
                sRC[t * 4 + 1] = (i == 44) ? 0.3f : (float)(-0.3 + i * (0.6 / 44.0));
                sRC[t * 4 + 2] = 0.f;
            } else {
                sRC[t * 4 + 0] = aload(&pts[rg * 3 + 0]);
                sRC[t * 4 + 1] = aload(&pts[rg * 3 + 1]);
                sRC[t * 4 + 2] = aload(&pts[rg * 3 + 2]);
            }
            sRC[t * 4 + 3] = __int_as_float(b - b0);
        }
        __syncthreads();

        float proj[2][4][3];
#pragma unroll
        for (int i = 0; i < 2; ++i)
#pragma unroll
            for (int r = 0; r < 4; ++r) { proj[i][r][0] = 0.f; proj[i][r][1] = 0.f; proj[i][r][2] = 0.f; }

        int sr = t >> 1, sh = t & 1;
        float4 rc = *(const float4*)&sRC[sr * 4];
        int ubi = __float_as_int(rc.w);
        const float* up = sU + ubi * 512;
        f32x4 acc[2][8];
#pragma unroll
        for (int i = 0; i < 2; ++i)
#pragma unroll
            for (int nt = 0; nt < 8; ++nt) acc[i][nt] = (f32x4){0.f, 0.f, 0.f, 0.f};
        for (int ks = 0; ks < 8; ++ks) {
            __syncthreads();
            {
                int cbase = ks * 64 + sh * 32;
                const float4* w0p = (const float4*)&sW[cbase];
                const float4* w1p = (const float4*)&sW[512 + cbase];
                const float4* w2p = (const float4*)&sW[1024 + cbase];
                const float4* uup = (const float4*)&up[cbase];
#pragma unroll
                for (int g4 = 0; g4 < 8; ++g4) {
                    float4 w0 = w0p[g4], w1 = w1p[g4], w2 = w2p[g4], uu = uup[g4];
                    float v0 = fmaf(rc.z, w2.x, fmaf(rc.y, w1.x, fmaf(rc.x, w0.x, uu.x)));
                    float v1 = fmaf(rc.z, w2.y, fmaf(rc.y, w1.y, fmaf(rc.x, w0.y, uu.y)));
                    float v2 = fmaf(rc.z, w2.z, fmaf(rc.y, w1.z, fmaf(rc.x, w0.z, uu.z)));
                    float v3 = fmaf(rc.z, w2.w, fmaf(rc.y, w1.w, fmaf(rc.x, w0.w, uu.w)));
                    uint2 pk;
                    pk.x = (unsigned)f2bf(fmaxf(v0, 0.f)) | ((unsigned)f2bf(fmaxf(v1, 0.f)) << 16);
                    pk.y = (unsigned)f2bf(fmaxf(v2, 0.f)) | ((unsigned)f2bf(fmaxf(v3, 0.f)) << 16);
                    *(uint2*)&As[sr * 72 + sh * 32 + g4 * 4] = pk;
                }
            }
            __syncthreads();
#pragma unroll
            for (int ks2 = 0; ks2 < 2; ++ks2) {
                bf16x8 afr0 = *(const bf16x8*)&As[((2 * wave) * 16 + l16) * 72 + ks2 * 32 + quad * 8];
                bf16x8 afr1 = *(const bf16x8*)&As[((2 * wave + 1) * 16 + l16) * 72 + ks2 * 32 + quad * 8];
#pragma unroll
                for (int nt = 0; nt < 8; ++nt) {
                    bf16x8 bfr = *(const bf16x8*)(WT + (size_t)(col0 + nt * 16 + l16) * 512 + ks * 64 + ks2 * 32 + quad * 8);
                    acc[0][nt] = MFMA16(afr0, bfr, acc[0][nt]);
                    acc[1][nt] = MFMA16(afr1, bfr, acc[1][nt]);
                }
            }
        }
#pragma unroll
        for (int i = 0; i < 2; ++i)
#pragma unroll
            for (int nt = 0; nt < 8; ++nt) {
                int lc = nt * 16 + l16;
                float bv = sB[lc];
                float w0 = sP[lc * 3 + 0], w1 = sP[lc * 3 + 1], w2 = sP[lc * 3 + 2];
#pragma unroll
                for (int reg = 0; reg < 4; ++reg) {
                    float h = fmaxf(acc[i][nt][reg] + bv, 0.f);
                    proj[i][reg][0] = fmaf(h, w0, proj[i][reg][0]);
                    proj[i][reg][1] = fmaf(h, w1, proj[i][reg][1]);
                    proj[i][reg][2] = fmaf(h, w2, proj[i][reg][2]);
                }
            }
        float o0 = (cc == 0) ? bout[0] : 0.f;
        float o1 = (cc == 0) ? bout[1] : 0.f;
        float o2 = (cc == 0) ? bout[2] : 0.f;
#pragma unroll
        for (int i = 0; i < 2; ++i)
#pragma unroll
            for (int reg = 0; reg < 4; ++reg) {
                float p0 = proj[i][reg][0], p1 = proj[i][reg][1], p2 = proj[i][reg][2];
#pragma unroll
                for (int m = 1; m < 16; m <<= 1) {
                    p0 += __shfl_xor(p0, m, 64);
                    p1 += __shfl_xor(p1, m, 64);
                    p2 += __shfl_xor(p2, m, 64);
                }
                if (l16 == 0) {
                    int row = row0 + (2 * wave + i) * 16 + quad * 4 + reg;
                    if (row < 16200) {
                        atomicAdd(&ov[row * 3 + 0], p0 + o0);
                        atomicAdd(&ov[row * 3 + 1], p1 + o1);
                        atomicAdd(&ov[row * 3 + 2], p2 + o2);
                    }
                }
            }
        if (dec == 0) {
            __syncthreads();
            if (t == 0) atomicAdd(&cnts[20 + j], 1);   // pts went via atomics: no fence
        }
    }
}

extern "C" void kernel_launch(void* const* d_in, const int* in_sizes, int n_in,
                              void* d_out, int out_size, void* d_ws, size_t ws_size,
                              hipStream_t stream) {
    const float* pos  = (const float*)d_in[0];
    const float* Wt   = (const float*)d_in[1];
    const float* bt   = (const float*)d_in[2];
    const float* Wc1  = (const float*)d_in[3];
    const float* bc1  = (const float*)d_in[4];
    const float* Wc2  = (const float*)d_in[5];
    const float* bc2  = (const float*)d_in[6];
    const float* Wc3  = (const float*)d_in[7];
    const float* bc3  = (const float*)d_in[8];
    const float* We1  = (const float*)d_in[9];
    const float* be1  = (const float*)d_in[10];
    const float* We2  = (const float*)d_in[11];
    const float* be2  = (const float*)d_in[12];
    const float* Wf11 = (const float*)d_in[13];
    const float* bf11 = (const float*)d_in[14];
    const float* Wf12 = (const float*)d_in[15];
    const float* bf12 = (const float*)d_in[16];
    const float* Wf13 = (const float*)d_in[17];
    const float* bf13 = (const float*)d_in[18];
    const float* Wf21 = (const float*)d_in[19];
    const float* bf21 = (const float*)d_in[20];
    const float* Wf22 = (const float*)d_in[21];
    const float* bf22 = (const float*)d_in[22];
    const float* Wf23 = (const float*)d_in[23];
    const float* bf23 = (const float*)d_in[24];
    float* out = (float*)d_out;

    float* wsf = (float*)d_ws;
    size_t off = 0;
    unsigned short* encinh= (unsigned short*)(wsf + off); off += 589824;   // [2048][576] bf16
    unsigned short* e1h   = (unsigned short*)(wsf + off); off += 524288;   // [2048][512] bf16
    float* zacc = wsf + off; off += 16384;     // [8][1024][2]
    float* u1   = wsf + off; off += 4096;
    float* u2   = wsf + off; off += 4096;
    float* pts  = wsf + off; off += 48600;     // [16200][3] (atomic-accumulated)
    float* newp = wsf + off; off += 6144;      // [B,S,3]
    int*   prog = (int*)(wsf + off); off += 16;
    int*   cnts = (int*)(wsf + off); off += 256;
    unsigned short* W1T   = (unsigned short*)(wsf + off); off += 3072;
    unsigned short* W2T   = (unsigned short*)(wsf + off); off += 4096;
    unsigned short* W3T   = (unsigned short*)(wsf + off); off += 32768;
    unsigned short* We1T  = (unsigned short*)(wsf + off); off += 147456;
    unsigned short* We2T  = (unsigned short*)(wsf + off); off += 524288;
    unsigned short* Wf12T = (unsigned short*)(wsf + off); off += 131072;
    unsigned short* Wf22T = (unsigned short*)(wsf + off); off += 131072;

    hipMemsetAsync(prog, 0xFF, 64, stream);
    hipMemsetAsync(cnts, 0x00, 1024, stream);
    hipMemsetAsync(zacc, 0x00, 16384 * 4, stream);
    hipMemsetAsync(pts, 0x00, 48600 * 4, stream);
    hipMemsetAsync(out, 0x00, (size_t)out_size * 4, stream);
    mega_kernel<<<4359, 256, 0, stream>>>(pos, newp, prog, cnts, Wt, bt,
                                          Wc1, Wc2, Wc3, We1, We2, Wf12, Wf22,
                                          W1T, W2T, W3T, We1T, We2T, Wf12T, Wf22T,
                                          bc1, bc2, bc3, encinh,
                                          be1, e1h, be2, zacc,
                                          Wf11, bf11, Wf21, bf21, u1, u2,
                                          bf12, Wf13, bf13, bf22, Wf23, bf23,
                                          pts, out);
}

// Round 17
// 781.015 us; speedup vs baseline: 1.0123x; 1.0123x over previous
//
#include <hip/hip_runtime.h>
#include <math.h>

#define BATCH 8
#define NPTS 4096
#define SSAMP 256
#define KNBR 128
#define GGRID 2025

typedef __attribute__((ext_vector_type(8))) short bf16x8;
typedef __attribute__((ext_vector_type(8))) unsigned short u16x8;
typedef __attribute__((ext_vector_type(4))) float f32x4;
#define MFMA16(a, b, c) __builtin_amdgcn_mfma_f32_16x16x32_bf16((a), (b), (c), 0, 0, 0)

__device__ __forceinline__ float lrelu01(float v) { return v > 0.f ? v : 0.01f * v; }
__device__ __forceinline__ unsigned short f2bf(float f) {
    unsigned u = __float_as_uint(f);
    unsigned r = (u + 0x7FFFu + ((u >> 16) & 1u)) >> 16;
    return (unsigned short)r;
}
__device__ __forceinline__ unsigned long long umax64(unsigned long long a, unsigned long long b) {
    return a > b ? a : b;
}
__device__ __forceinline__ void spin_ge(const int* p, int target) {
    while (__hip_atomic_load(p, __ATOMIC_RELAXED, __HIP_MEMORY_SCOPE_AGENT) < target)
        __builtin_amdgcn_s_sleep(16);
}
__device__ __forceinline__ void spin_ge_slow(const int* p, int target) {
    while (__hip_atomic_load(p, __ATOMIC_RELAXED, __HIP_MEMORY_SCOPE_AGENT) < target)
        __builtin_amdgcn_s_sleep(64);   // coarse poll: don't hammer the coherent point during fps
}
__device__ __forceinline__ float aload(const float* p) {
    return __hip_atomic_load((float*)p, __ATOMIC_RELAXED, __HIP_MEMORY_SCOPE_AGENT);
}
__device__ __forceinline__ void astore(float* p, float v) {
    __hip_atomic_store(p, v, __ATOMIC_RELAXED, __HIP_MEMORY_SCOPE_AGENT);
}

// ---------------------------------------------------------------- launch 1: preconv part 1
// W1T/W2T/W3T/We1T only (183 blocks x 2048 elems = 374784 exact). Consumers of these read
// them in LATER LAUNCHES -> visible by stream order, no flags needed.
__global__ void preconv1_kernel(const float* __restrict__ Wc1, const float* __restrict__ Wc2,
                                const float* __restrict__ Wc3, const float* __restrict__ We1,
                                unsigned short* __restrict__ W1T, unsigned short* __restrict__ W2T,
                                unsigned short* __restrict__ W3T, unsigned short* __restrict__ We1T) {
    int o = blockIdx.x * 256 + threadIdx.x;
    const int S1 = 6144, S2 = 8192, S3 = 65536;
#pragma unroll
    for (int j = 0; j < 8; ++j) {
        int q = o + j * 47104;   // 184*256
        if (q >= 374784) continue;
        if (q < S1) { int n = q / 96, k = q - n * 96; W1T[q] = f2bf(k < 67 ? Wc1[k * 64 + n] : 0.f); continue; }
        q -= S1;
        if (q < S2) { int n = q >> 6, k = q & 63; W2T[q] = f2bf(Wc2[k * 128 + n]); continue; }
        q -= S2;
        if (q < S3) { int n = q >> 7, k = q & 127; W3T[q] = f2bf(Wc3[k * 512 + n]); continue; }
        q -= S3;
        { int n = q / 576, k = q - n * 576; We1T[q] = f2bf(k < 515 ? We1[k * 512 + n] : 0.f); }
    }
}

// ---------------------------------------------------------------- stage1: fps (0-7) + consumers (8..2055)
__global__ void __launch_bounds__(256, 3) stage1_kernel(
    const float* __restrict__ pos, float* __restrict__ newpos, int* __restrict__ prog,
    const float* __restrict__ Wt, const float* __restrict__ bt,
    const unsigned short* __restrict__ W1T, const unsigned short* __restrict__ W2T,
    const unsigned short* __restrict__ W3T,
    const float* __restrict__ bc1, const float* __restrict__ bc2, const float* __restrict__ bc3,
    unsigned short* __restrict__ encin) {
    __shared__ __align__(16) unsigned char smem[53760];
    int blk = blockIdx.x, t = threadIdx.x;
    int wave = t >> 6, lane = t & 63;

    if (blk < 8) {
        float* pxs = (float*)smem;
        float* pys = (float*)(smem + 16384);
        float* pzs = (float*)(smem + 32768);
        float* npb = (float*)(smem + 49152);
        unsigned long long* rk = (unsigned long long*)(smem + 52224);
        int b = blk;
        const float* P = pos + (size_t)b * NPTS * 3;
        float* np = newpos + (size_t)b * SSAMP * 3;
        float px[16], py[16], pz[16], mind[16];
#pragma unroll
        for (int j = 0; j < 16; ++j) {
            int n = t + 256 * j;
            float X = P[n * 3 + 0], Y = P[n * 3 + 1], Z = P[n * 3 + 2];
            px[j] = X; py[j] = Y; pz[j] = Z;
            pxs[n] = X; pys[n] = Y; pzs[n] = Z;
            mind[j] = 3.402823466e+38f;
        }
        float cx = P[0], cy = P[1], cz = P[2];
        if (t == 0) { npb[0] = cx; npb[1] = cy; npb[2] = cz; }
        __syncthreads();
        for (int s = 1; s < SSAMP; ++s) {
            int p = s & 1;
            unsigned long long k[16];
#pragma unroll
            for (int j = 0; j < 16; ++j) {
                float dx = __fsub_rn(px[j], cx), dy = __fsub_rn(py[j], cy), dz = __fsub_rn(pz[j], cz);
                float d = __fadd_rn(__fadd_rn(__fmul_rn(dx, dx), __fmul_rn(dy, dy)), __fmul_rn(dz, dz));
                mind[j] = fminf(mind[j], d);
                k[j] = ((unsigned long long)__float_as_uint(mind[j]) << 32)
                     | (unsigned)~(unsigned)(t + 256 * j);
            }
#pragma unroll
            for (int st = 8; st > 0; st >>= 1)
#pragma unroll
                for (int j = 0; j < st; ++j) k[j] = umax64(k[j], k[j + st]);
            unsigned long long key = k[0];
            {
                unsigned long long a = __shfl_xor(key, 1, 64);
                unsigned long long b2 = __shfl_xor(key, 2, 64);
                unsigned long long c = __shfl_xor(key, 3, 64);
                key = umax64(umax64(key, a), umax64(b2, c));
                a = __shfl_xor(key, 4, 64);
                b2 = __shfl_xor(key, 8, 64);
                c = __shfl_xor(key, 12, 64);
                key = umax64(umax64(key, a), umax64(b2, c));
                a = __shfl_xor(key, 16, 64);
                b2 = __shfl_xor(key, 32, 64);
                c = __shfl_xor(key, 48, 64);
                key = umax64(umax64(key, a), umax64(b2, c));
            }
            if (lane == 0) rk[p * 4 + wave] = key;
            __syncthreads();
            unsigned long long k0 = rk[p * 4 + 0], k1 = rk[p * 4 + 1];
            unsigned long long k2 = rk[p * 4 + 2], k3 = rk[p * 4 + 3];
            unsigned long long bk = umax64(umax64(k0, k1), umax64(k2, k3));
            int nx = (int)(~(unsigned)(bk & 0xFFFFFFFFull));
            cx = pxs[nx]; cy = pys[nx]; cz = pzs[nx];
            if (t == 0) {
                npb[s * 3 + 0] = cx;
                npb[s * 3 + 1] = cy;
                npb[s * 3 + 2] = cz;
            }
            if ((s & 7) == 7) {
                if (t < 24) astore(&np[(s - 7) * 3 + t], npb[(s - 7) * 3 + t]);
                if (t == 0 && s >= 15)
                    __hip_atomic_store(&prog[b], s - 8, __ATOMIC_RELAXED, __HIP_MEMORY_SCOPE_AGENT);
            }
        }
        __syncthreads();
        if (t == 0)
            __hip_atomic_store(&prog[b], 255, __ATOMIC_RELAXED, __HIP_MEMORY_SCOPE_AGENT);
        return;
    }

    unsigned short* featl = (unsigned short*)smem;
    unsigned short* h2    = (unsigned short*)smem;
    unsigned short* h1    = (unsigned short*)(smem + 34816);
    float* mred = (float*)(smem + 34816);
    int*   vld  = (int*)(smem + 53248);
    int*   wl   = (int*)smem;
    int*   cnt  = (int*)(smem + 2048);
    float* wtb  = (float*)(smem + 26624);

    int cons = blk - 8;
    int s = cons >> 3, b = cons & 7;
    int bs = b * 256 + s;
    int quad = lane >> 4, l16 = lane & 15;

    if (t == 0) spin_ge_slow(&prog[b], s);
    __syncthreads();
    float q0 = aload(&newpos[(size_t)bs * 3 + 0]);
    float q1 = aload(&newpos[(size_t)bs * 3 + 1]);
    float q2 = aload(&newpos[(size_t)bs * 3 + 2]);

    const float* P = pos + (size_t)b * NPTS * 3;
    {
        int base = 0;
        for (int c = 0; c < 16 && base < KNBR; ++c) {
            int n = wave * 1024 + c * 64 + lane;
            float dx = __fsub_rn(P[n * 3 + 0], q0);
            float dy = __fsub_rn(P[n * 3 + 1], q1);
            float dz = __fsub_rn(P[n * 3 + 2], q2);
            float d2 = __fadd_rn(__fadd_rn(__fmul_rn(dx, dx), __fmul_rn(dy, dy)), __fmul_rn(dz, dz));
            bool in = (d2 <= 0.04f);
            unsigned long long mask = __ballot(in);
            if (in) {
                int p = base + __popcll(mask & ((1ull << lane) - 1ull));
                if (p < KNBR) wl[wave * 128 + p] = n;
            }
            base += __popcll(mask);
        }
        if (lane == 0) cnt[wave] = base < KNBR ? base : KNBR;
    }
    __syncthreads();
    {
        int c0 = cnt[0], c1 = cnt[1], c2 = cnt[2], c3 = cnt[3];
        if (t < 128) {
            int idx = -1, r = t;
            if (r < c0) idx = wl[r];
            else {
                r -= c0;
                if (r < c1) idx = wl[128 + r];
                else {
                    r -= c1;
                    if (r < c2) idx = wl[256 + r];
                    else { r -= c2; if (r < c3) idx = wl[384 + r]; }
                }
            }
            vld[t] = idx;
        }
        if (t < 192) wtb[t] = Wt[t];
        else wtb[t] = bt[t - 192];
    }
    __syncthreads();

    int vbits = 0;
#pragma unroll
    for (int i = 0; i < 2; ++i)
#pragma unroll
        for (int reg = 0; reg < 4; ++reg)
            if (vld[(2 * wave + i) * 16 + quad * 4 + reg] >= 0) vbits |= 1 << (i * 4 + reg);

    {
        int sr = t >> 1, sh = t & 1;
        int n = vld[sr];
        int ns = n < 0 ? 0 : n;
        const float* pp = pos + ((size_t)b * NPTS + ns) * 3;
        float p0 = pp[0], p1 = pp[1], p2 = pp[2];
        unsigned short* frow = &featl[sr * 104];
        u16x8 z8 = {0, 0, 0, 0, 0, 0, 0, 0};
        if (n >= 0) {
#pragma unroll
            for (int g = 0; g < 4; ++g) {
                u16x8 v8;
#pragma unroll
                for (int e = 0; e < 8; ++e) {
                    int c = sh * 32 + g * 8 + e;
                    float v = fmaf(p2, wtb[128 + c], fmaf(p1, wtb[64 + c], fmaf(p0, wtb[c], wtb[192 + c])));
                    v8[e] = (unsigned short)f2bf(lrelu01(v));
                }
                *(u16x8*)&frow[sh * 32 + g * 8] = v8;
            }
        } else {
#pragma unroll
            for (int g = 0; g < 4; ++g) *(u16x8*)&frow[sh * 32 + g * 8] = z8;
        }
        if (sh == 1) {
            u16x8 dv = z8;
            if (n >= 0) {
                dv[0] = (unsigned short)f2bf(__fsub_rn(p0, q0));
                dv[1] = (unsigned short)f2bf(__fsub_rn(p1, q1));
                dv[2] = (unsigned short)f2bf(__fsub_rn(p2, q2));
            }
            *(u16x8*)&frow[64] = dv;
            *(u16x8*)&frow[72] = z8;
            *(u16x8*)&frow[80] = z8;
            *(u16x8*)&frow[88] = z8;
        }
    }
    __syncthreads();

    {
        f32x4 acc[2][4];
#pragma unroll
        for (int i = 0; i < 2; ++i)
#pragma unroll
            for (int nt = 0; nt < 4; ++nt) acc[i][nt] = (f32x4){0.f, 0.f, 0.f, 0.f};
#pragma unroll
        for (int ks = 0; ks < 3; ++ks) {
            bf16x8 afr[2];
#pragma unroll
            for (int i = 0; i < 2; ++i)
                afr[i] = *(const bf16x8*)&featl[((2 * wave + i) * 16 + l16) * 104 + ks * 32 + quad * 8];
#pragma unroll
            for (int nt = 0; nt < 4; ++nt) {
                bf16x8 bfr = *(const bf16x8*)(W1T + (nt * 16 + l16) * 96 + ks * 32 + quad * 8);
                acc[0][nt] = MFMA16(afr[0], bfr, acc[0][nt]);
                acc[1][nt] = MFMA16(afr[1], bfr, acc[1][nt]);
            }
        }
#pragma unroll
        for (int i = 0; i < 2; ++i)
#pragma unroll
            for (int nt = 0; nt < 4; ++nt) {
                int col = nt * 16 + l16;
                float bias = bc1[col];
#pragma unroll
                for (int reg = 0; reg < 4; ++reg) {
                    int row = (2 * wave + i) * 16 + quad * 4 + reg;
                    h1[row * 72 + col] = f2bf(lrelu01(acc[i][nt][reg] + bias));
                }
            }
    }
    __syncthreads();

    {
        f32x4 acc[2][8];
#pragma unroll
        for (int i = 0; i < 2; ++i)
#pragma unroll
            for (int nt = 0; nt < 8; ++nt) acc[i][nt] = (f32x4){0.f, 0.f, 0.f, 0.f};
#pragma unroll
        for (int ks = 0; ks < 2; ++ks) {
            bf16x8 afr[2];
#pragma unroll
            for (int i = 0; i < 2; ++i)
                afr[i] = *(const bf16x8*)&h1[((2 * wave + i) * 16 + l16) * 72 + ks * 32 + quad * 8];
#pragma unroll
            for (int nt = 0; nt < 8; ++nt) {
                bf16x8 bfr = *(const bf16x8*)(W2T + (nt * 16 + l16) * 64 + ks * 32 + quad * 8);
                acc[0][nt] = MFMA16(afr[0], bfr, acc[0][nt]);
                acc[1][nt] = MFMA16(afr[1], bfr, acc[1][nt]);
            }
        }
        __syncthreads();
#pragma unroll
        for (int i = 0; i < 2; ++i)
#pragma unroll
            for (int nt = 0; nt < 8; ++nt) {
                int col = nt * 16 + l16;
                float bias = bc2[col];
#pragma unroll
                for (int reg = 0; reg < 4; ++reg) {
                    int row = (2 * wave + i) * 16 + quad * 4 + reg;
                    h2[row * 136 + col] = f2bf(lrelu01(acc[i][nt][reg] + bias));
                }
            }
    }
    __syncthreads();

    for (int c3 = 0; c3 < 4; ++c3) {
        f32x4 acc[2][8];
#pragma unroll
        for (int i = 0; i < 2; ++i)
#pragma unroll
            for (int nt = 0; nt < 8; ++nt) acc[i][nt] = (f32x4){0.f, 0.f, 0.f, 0.f};
#pragma unroll
        for (int ks = 0; ks < 4; ++ks) {
            bf16x8 afr[2];
#pragma unroll
            for (int i = 0; i < 2; ++i)
                afr[i] = *(const bf16x8*)&h2[((2 * wave + i) * 16 + l16) * 136 + ks * 32 + quad * 8];
#pragma unroll
            for (int nt = 0; nt < 8; ++nt) {
                bf16x8 bfr = *(const bf16x8*)(W3T + ((size_t)((c3 * 8 + nt) * 16 + l16)) * 128 + ks * 32 + quad * 8);
                acc[0][nt] = MFMA16(afr[0], bfr, acc[0][nt]);
                acc[1][nt] = MFMA16(afr[1], bfr, acc[1][nt]);
            }
        }
#pragma unroll
        for (int nt = 0; nt < 8; ++nt) {
            float vmax = -3.402823466e+38f;
#pragma unroll
            for (int i = 0; i < 2; ++i)
#pragma unroll
                for (int reg = 0; reg < 4; ++reg)
                    if (vbits & (1 << (i * 4 + reg))) vmax = fmaxf(vmax, acc[i][nt][reg]);
            vmax = fmaxf(vmax, __shfl_xor(vmax, 16));
            vmax = fmaxf(vmax, __shfl_xor(vmax, 32));
            if (lane < 16) mred[wave * 512 + (c3 * 8 + nt) * 16 + l16] = vmax;
        }
    }
    __syncthreads();
    unsigned short* erow = encin + (size_t)bs * 576;
    for (int c = t; c < 576; c += 256) {
        unsigned short v;
        if (c < 512) {
            float m4 = fmaxf(fmaxf(mred[c], mred[512 + c]), fmaxf(mred[1024 + c], mred[1536 + c]));
            v = f2bf(lrelu01(m4 + bc3[c]));
        } else if (c < 515) {
            v = f2bf(c == 512 ? q0 : (c == 513 ? q1 : q2));
        } else v = 0;
        erow[c] = v;
    }
}

// ---------------------------------------------------------------- tail: 2120 blocks.
// [0,768) preconv p2 (We2T 512 -> cnts[148], WfT 256 -> cnts[149]) runs under e1;
// [768,832) e1 -> cnts[rb]; [832,1088) e2v -> cnts[16]; [1088,1104) ukern -> cnts[17]/[18];
// [1104,1612) ff1 (j,cc) -> pts atomics + cnts[20+j]; [1612,2120) ff2 -> out atomics.
__global__ void __launch_bounds__(256, 2) tail_kernel(
    const float* __restrict__ We2, const float* __restrict__ Wf12, const float* __restrict__ Wf22,
    unsigned short* __restrict__ We2T, unsigned short* __restrict__ Wf12T,
    unsigned short* __restrict__ Wf22T,
    const unsigned short* __restrict__ encinh, const unsigned short* __restrict__ We1T,
    const float* __restrict__ be1, unsigned short* __restrict__ e1h,
    const float* __restrict__ be2,
    float* __restrict__ zacc, int* __restrict__ cnts,
    const float* __restrict__ Wf11, const float* __restrict__ bf11,
    const float* __restrict__ Wf21, const float* __restrict__ bf21,
    float* __restrict__ u1, float* __restrict__ u2,
    const float* __restrict__ bf12,
    const float* __restrict__ Wf13, const float* __restrict__ bf13,
    const float* __restrict__ bf22,
    const float* __restrict__ Wf23, const float* __restrict__ bf23,
    float* __restrict__ pts, float* __restrict__ outv) {
    __shared__ __align__(16) unsigned char smem[40960];
    int blk = blockIdx.x, t = threadIdx.x;
    int wave = t >> 6, lane = t & 63, quad = lane >> 4, l16 = lane & 15;

    if (blk < 768) {
        // ---------- preconv p2: S5 We2T (1048576), S6 Wf12T (262144), S7 Wf22T (262144)
        const int S5 = 1048576, S6 = 262144;
#pragma unroll
        for (int j = 0; j < 8; ++j) {
            int q = blk * 2048 + t + j * 256;
            if (q < S5) {
                int np2 = q >> 9, k = q & 511;
                int src = (np2 & 1) ? 1024 + (np2 >> 1) : (np2 >> 1);
                We2T[q] = f2bf(We2[(size_t)k * 2048 + src]);
                continue;
            }
            q -= S5;
            if (q < S6) { int n = q >> 9, k = q & 511; Wf12T[q] = f2bf(Wf12[k * 512 + n]); continue; }
            q -= S6;
            { int n = q >> 9, k = q & 511; Wf22T[q] = f2bf(Wf22[k * 512 + n]); }
        }
        __syncthreads();
        if (t == 0) {
            __threadfence();
            atomicAdd(&cnts[blk < 512 ? 148 : 149], 1);
        }
        return;
    }

    if (blk < 1088) {
        // ---------- e1 (768..832) or e2v (832..1088) ----------
        unsigned short* As = (unsigned short*)smem;
        bool is_e1 = blk < 832;
        int rb, cb;
        const unsigned short* A;
        const unsigned short* BT;
        int Ka;
        if (is_e1) { int j = blk - 768; rb = j >> 2; cb = j & 3; A = encinh; BT = We1T; Ka = 576; }
        else {
            int j = blk - 832; rb = j >> 4; cb = j & 15; A = e1h; BT = We2T; Ka = 512;
            if (t == 0) { spin_ge(&cnts[148], 512); spin_ge(&cnts[rb], 4); }
            __syncthreads();
            __threadfence();   // acquire e1h + We2T (normal stores)
        }
        int row0 = rb * 128, col0 = cb * 128;
        f32x4 acc[2][8];
#pragma unroll
        for (int i = 0; i < 2; ++i)
#pragma unroll
            for (int nt = 0; nt < 8; ++nt) acc[i][nt] = (f32x4){0.f, 0.f, 0.f, 0.f};
        int nk = Ka >> 6;
        int sr = t >> 1, sh = t & 1;
        const unsigned short* Arow = A + (size_t)(row0 + sr) * Ka + sh * 32;
        for (int ks = 0; ks < nk; ++ks) {
            u16x8 av[4];
#pragma unroll
            for (int j = 0; j < 4; ++j) av[j] = *(const u16x8*)(Arow + ks * 64 + j * 8);
            __syncthreads();
#pragma unroll
            for (int j = 0; j < 4; ++j) *(u16x8*)&As[sr * 72 + sh * 32 + j * 8] = av[j];
            __syncthreads();
#pragma unroll
            for (int ks2 = 0; ks2 < 2; ++ks2) {
                bf16x8 afr0 = *(const bf16x8*)&As[((2 * wave) * 16 + l16) * 72 + ks2 * 32 + quad * 8];
                bf16x8 afr1 = *(const bf16x8*)&As[((2 * wave + 1) * 16 + l16) * 72 + ks2 * 32 + quad * 8];
#pragma unroll
                for (int nt = 0; nt < 8; ++nt) {
                    bf16x8 bfr = *(const bf16x8*)(BT + (size_t)(col0 + nt * 16 + l16) * Ka + ks * 64 + ks2 * 32 + quad * 8);
                    acc[0][nt] = MFMA16(afr0, bfr, acc[0][nt]);
                    acc[1][nt] = MFMA16(afr1, bfr, acc[1][nt]);
                }
            }
        }
        if (is_e1) {
#pragma unroll
            for (int i = 0; i < 2; ++i)
#pragma unroll
                for (int nt = 0; nt < 8; ++nt) {
                    int col = col0 + nt * 16 + l16;
                    float bv = be1[col];
#pragma unroll
                    for (int reg = 0; reg < 4; ++reg) {
                        int row = row0 + (2 * wave + i) * 16 + quad * 4 + reg;
                        e1h[(size_t)row * 512 + col] = f2bf(lrelu01(acc[i][nt][reg] + bv));
                    }
                }
            __syncthreads();
            if (t == 0) { __threadfence(); atomicAdd(&cnts[rb], 1); }
        } else {
            int b = row0 >> 8;
#pragma unroll
            for (int nt = 0; nt < 8; ++nt) {
                int colp = col0 + nt * 16 + l16;
                int c2 = colp >> 1;
                int srcc = (colp & 1) ? 1024 + c2 : c2;
                float bv = be2[srcc];
                float num = 0.f, den = 0.f;
#pragma unroll
                for (int i = 0; i < 2; ++i)
#pragma unroll
                    for (int reg = 0; reg < 4; ++reg) {
                        float val = acc[i][nt][reg] + bv;
                        float par = __shfl_xor(val, 1, 64);
                        float d = expf(-0.5f * par);
                        num += val * d;
                        den += d;
                    }
                num += __shfl_xor(num, 16, 64); den += __shfl_xor(den, 16, 64);
                num += __shfl_xor(num, 32, 64); den += __shfl_xor(den, 32, 64);
                if (quad == 0 && !(l16 & 1)) {
                    atomicAdd(&zacc[((b << 10) + c2) * 2 + 0], num);
                    atomicAdd(&zacc[((b << 10) + c2) * 2 + 1], den);
                }
            }
            __syncthreads();
            if (t == 0) atomicAdd(&cnts[16], 1);
        }
        return;
    }

    if (blk < 1104) {
        // ---------- ukern ----------
        float* zt = (float*)smem;
        float* red = (float*)(smem + 32768);
        int j = blk - 1088;
        int dec = j >> 3, cb = j & 7;
        const float* W = dec ? Wf21 : Wf11;
        const float* bias = dec ? bf21 : bf11;
        float* u = dec ? u2 : u1;
        if (t == 0) spin_ge(&cnts[16], 256);
        __syncthreads();
#pragma unroll
        for (int i = 0; i < 32; ++i) {
            int o = t + i * 256;
            float num = aload(&zacc[o * 2 + 0]);
            float den = aload(&zacc[o * 2 + 1]);
            zt[(o & 1023) * 8 + (o >> 10)] = num / den;
        }
        __syncthreads();
        int c64 = t & 63, kc = t >> 6;
        int co = cb * 64 + c64;
        float acc[8];
#pragma unroll
        for (int r = 0; r < 8; ++r) acc[r] = 0.f;
        for (int i = 0; i < 256; ++i) {
            int ci = kc * 256 + i;
            float w = W[(size_t)ci * 512 + co];
            const float4* zp = (const float4*)&zt[ci * 8];
            float4 z0 = zp[0], z1 = zp[1];
            acc[0] = fmaf(z0.x, w, acc[0]); acc[1] = fmaf(z0.y, w, acc[1]);
            acc[2] = fmaf(z0.z, w, acc[2]); acc[3] = fmaf(z0.w, w, acc[3]);
            acc[4] = fmaf(z1.x, w, acc[4]); acc[5] = fmaf(z1.y, w, acc[5]);
            acc[6] = fmaf(z1.z, w, acc[6]); acc[7] = fmaf(z1.w, w, acc[7]);
        }
#pragma unroll
        for (int r = 0; r < 8; ++r) red[(kc * 64 + c64) * 8 + r] = acc[r];
        __syncthreads();
        if (kc == 0) {
#pragma unroll
            for (int r = 0; r < 8; ++r) {
                float v = red[(0 * 64 + c64) * 8 + r] + red[(1 * 64 + c64) * 8 + r]
                        + red[(2 * 64 + c64) * 8 + r] + red[(3 * 64 + c64) * 8 + r] + bias[co];
                astore(&u[r * 512 + co], v);
            }
        }
        __syncthreads();
        if (t == 0) atomicAdd(&cnts[17 + dec], 1);
        return;
    }

    // ---------- foldfuse (j,cc): ff1 1104..1612, ff2 1612..2120 ----------
    {
        unsigned short* As = (unsigned short*)smem;          // 18432
        float* sW = (float*)(smem + 18432);                  // [3][512]
        float* sU = (float*)(smem + 24576);                  // [2][512]
        float* sP = (float*)(smem + 28672);                  // [128*3]
        float* sB = (float*)(smem + 30208);                  // [128]
        float* sRC = (float*)(smem + 30720);                 // [128][4]
        int dec = blk < 1612 ? 0 : 1;
        int idx0 = blk - (dec ? 1612 : 1104);
        int j = idx0 >> 2, cc = idx0 & 3;
        const float* u = dec ? u2 : u1;
        const float* Wfold = dec ? Wf21 : Wf11;
        int nExtra = dec ? 3 : 2;
        const unsigned short* WT = dec ? Wf22T : Wf12T;
        const float* bmid = dec ? bf22 : bf12;
        const float* wout = dec ? Wf23 : Wf13;
        const float* bout = dec ? bf23 : bf13;
        float* ov = dec ? outv : pts;
        int row0 = j * 128, col0 = cc * 128;
        int b0 = row0 / 2025;

        // -------- static preloads BEFORE the spin (inputs only; hides latency) --------
        for (int idx = t; idx < 1536; idx += 256) {
            int r = idx >> 9, c = idx & 511;
            sW[r * 512 + c] = (r < nExtra) ? Wfold[(size_t)(1024 + r) * 512 + c] : 0.f;
        }
        for (int idx = t; idx < 384; idx += 256) sP[idx] = wout[col0 * 3 + idx];
        if (t < 128) sB[t] = bmid[col0 + t];
        if (dec == 0 && t < 128) {
            int rg = row0 + t; if (rg > 16199) rg = 16199;
            int b = rg / 2025, g = rg - b * 2025;
            int i = g / 45, jj = g - i * 45;
            sRC[t * 4 + 0] = (jj == 44) ? 0.3f : (float)(-0.3 + jj * (0.6 / 44.0));
            sRC[t * 4 + 1] = (i == 44) ? 0.3f : (float)(-0.3 + i * (0.6 / 44.0));
            sRC[t * 4 + 2] = 0.f;
            sRC[t * 4 + 3] = __int_as_float(b - b0);
        }

        if (t == 0) {
            spin_ge(&cnts[149], 256);
            spin_ge(&cnts[17 + dec], 8);
            if (dec) spin_ge(&cnts[20 + j], 4);
        }
        __syncthreads();
        __threadfence();   // acquire WfT (normal stores from preconv p2)

        for (int idx = t; idx < 1024; idx += 256) {
            int rb = idx >> 9;
            int bb = b0 + rb; if (bb > 7) bb = 7;
            sU[rb * 512 + (idx & 511)] = aload(&u[bb * 512 + (idx & 511)]);
        }
        if (dec == 1 && t < 128) {
            int rg = row0 + t; if (rg > 16199) rg = 16199;
            int b = rg / 2025;
            sRC[t * 4 + 0] = aload(&pts[rg * 3 + 0]);
            sRC[t * 4 + 1] = aload(&pts[rg * 3 + 1]);
            sRC[t * 4 + 2] = aload(&pts[rg * 3 + 2]);
            sRC[t * 4 + 3] = __int_as_float(b - b0);
        }
        __syncthreads();

        float proj[2][4][3];
#pragma unroll
        for (int i = 0; i < 2; ++i)
#pragma unroll
            for (int r = 0; r < 4; ++r) { proj[i][r][0] = 0.f; proj[i][r][1] = 0.f; proj[i][r][2] = 0.f; }

        int sr = t >> 1, sh = t & 1;
        float4 rc = *(const float4*)&sRC[sr * 4];
        int ubi = __float_as_int(rc.w);
        const float* up = sU + ubi * 512;
        f32x4 acc[2][8];
#pragma unroll
        for (int i = 0; i < 2; ++i)
#pragma unroll
            for (int nt = 0; nt < 8; ++nt) acc[i][nt] = (f32x4){0.f, 0.f, 0.f, 0.f};
        for (int ks = 0; ks < 8; ++ks) {
            __syncthreads();
            {
                int cbase = ks * 64 + sh * 32;
                const float4* w0p = (const float4*)&sW[cbase];
                const float4* w1p = (const float4*)&sW[512 + cbase];
                const float4* w2p = (const float4*)&sW[1024 + cbase];
                const float4* uup = (const float4*)&up[cbase];
#pragma unroll
                for (int g4 = 0; g4 < 8; ++g4) {
                    float4 w0 = w0p[g4], w1 = w1p[g4], w2 = w2p[g4], uu = uup[g4];
                    float v0 = fmaf(rc.z, w2.x, fmaf(rc.y, w1.x, fmaf(rc.x, w0.x, uu.x)));
                    float v1 = fmaf(rc.z, w2.y, fmaf(rc.y, w1.y, fmaf(rc.x, w0.y, uu.y)));
                    float v2 = fmaf(rc.z, w2.z, fmaf(rc.y, w1.z, fmaf(rc.x, w0.z, uu.z)));
                    float v3 = fmaf(rc.z, w2.w, fmaf(rc.y, w1.w, fmaf(rc.x, w0.w, uu.w)));
                    uint2 pk;
                    pk.x = (unsigned)f2bf(fmaxf(v0, 0.f)) | ((unsigned)f2bf(fmaxf(v1, 0.f)) << 16);
                    pk.y = (unsigned)f2bf(fmaxf(v2, 0.f)) | ((unsigned)f2bf(fmaxf(v3, 0.f)) << 16);
                    *(uint2*)&As[sr * 72 + sh * 32 + g4 * 4] = pk;
                }
            }
            __syncthreads();
#pragma unroll
            for (int ks2 = 0; ks2 < 2; ++ks2) {
                bf16x8 afr0 = *(const bf16x8*)&As[((2 * wave) * 16 + l16) * 72 + ks2 * 32 + quad * 8];
                bf16x8 afr1 = *(const bf16x8*)&As[((2 * wave + 1) * 16 + l16) * 72 + ks2 * 32 + quad * 8];
#pragma unroll
                for (int nt = 0; nt < 8; ++nt) {
                    bf16x8 bfr = *(const bf16x8*)(WT + (size_t)(col0 + nt * 16 + l16) * 512 + ks * 64 + ks2 * 32 + quad * 8);
                    acc[0][nt] = MFMA16(afr0, bfr, acc[0][nt]);
                    acc[1][nt] = MFMA16(afr1, bfr, acc[1][nt]);
                }
            }
        }
#pragma unroll
        for (int i = 0; i < 2; ++i)
#pragma unroll
            for (int nt = 0; nt < 8; ++nt) {
                int lc = nt * 16 + l16;
                float bv = sB[lc];
                float w0 = sP[lc * 3 + 0], w1 = sP[lc * 3 + 1], w2 = sP[lc * 3 + 2];
#pragma unroll
                for (int reg = 0; reg < 4; ++reg) {
                    float h = fmaxf(acc[i][nt][reg] + bv, 0.f);
                    proj[i][reg][0] = fmaf(h, w0, proj[i][reg][0]);
                    proj[i][reg][1] = fmaf(h, w1, proj[i][reg][1]);
                    proj[i][reg][2] = fmaf(h, w2, proj[i][reg][2]);
                }
            }
        float o0 = (cc == 0) ? bout[0] : 0.f;
        float o1 = (cc == 0) ? bout[1] : 0.f;
        float o2 = (cc == 0) ? bout[2] : 0.f;
#pragma unroll
        for (int i = 0; i < 2; ++i)
#pragma unroll
            for (int reg = 0; reg < 4; ++reg) {
                float p0 = proj[i][reg][0], p1 = proj[i][reg][1], p2 = proj[i][reg][2];
#pragma unroll
                for (int m = 1; m < 16; m <<= 1) {
                    p0 += __shfl_xor(p0, m, 64);
                    p1 += __shfl_xor(p1, m, 64);
                    p2 += __shfl_xor(p2, m, 64);
                }
                if (l16 == 0) {
                    int row = row0 + (2 * wave + i) * 16 + quad * 4 + reg;
                    if (row < 16200) {
                        atomicAdd(&ov[row * 3 + 0], p0 + o0);
                        atomicAdd(&ov[row * 3 + 1], p1 + o1);
                        atomicAdd(&ov[row * 3 + 2], p2 + o2);
                    }
                }
            }
        if (dec == 0) {
            __syncthreads();
            if (t == 0) atomicAdd(&cnts[20 + j], 1);
        }
    }
}

extern "C" void kernel_launch(void* const* d_in, const int* in_sizes, int n_in,
                              void* d_out, int out_size, void* d_ws, size_t ws_size,
                              hipStream_t stream) {
    const float* pos  = (const float*)d_in[0];
    const float* Wt   = (const float*)d_in[1];
    const float* bt   = (const float*)d_in[2];
    const float* Wc1  = (const float*)d_in[3];
    const float* bc1  = (const float*)d_in[4];
    const float* Wc2  = (const float*)d_in[5];
    const float* bc2  = (const float*)d_in[6];
    const float* Wc3  = (const float*)d_in[7];
    const float* bc3  = (const float*)d_in[8];
    const float* We1  = (const float*)d_in[9];
    const float* be1  = (const float*)d_in[10];
    const float* We2  = (const float*)d_in[11];
    const float* be2  = (const float*)d_in[12];
    const float* Wf11 = (const float*)d_in[13];
    const float* bf11 = (const float*)d_in[14];
    const float* Wf12 = (const float*)d_in[15];
    const float* bf12 = (const float*)d_in[16];
    const float* Wf13 = (const float*)d_in[17];
    const float* bf13 = (const float*)d_in[18];
    const float* Wf21 = (const float*)d_in[19];
    const float* bf21 = (const float*)d_in[20];
    const float* Wf22 = (const float*)d_in[21];
    const float* bf22 = (const float*)d_in[22];
    const float* Wf23 = (const float*)d_in[23];
    const float* bf23 = (const float*)d_in[24];
    float* out = (float*)d_out;

    float* wsf = (float*)d_ws;
    size_t off = 0;
    unsigned short* encinh= (unsigned short*)(wsf + off); off += 589824;   // [2048][576] bf16
    unsigned short* e1h   = (unsigned short*)(wsf + off); off += 524288;   // [2048][512] bf16
    float* zacc = wsf + off; off += 16384;     // [8][1024][2]
    float* u1   = wsf + off; off += 4096;
    float* u2   = wsf + off; off += 4096;
    float* pts  = wsf + off; off += 48600;     // [16200][3] (atomic-accumulated)
    float* newp = wsf + off; off += 6144;      // [B,S,3]
    int*   prog = (int*)(wsf + off); off += 16;
    int*   cnts = (int*)(wsf + off); off += 256;
    unsigned short* W1T   = (unsigned short*)(wsf + off); off += 3072;
    unsigned short* W2T   = (unsigned short*)(wsf + off); off += 4096;
    unsigned short* W3T   = (unsigned short*)(wsf + off); off += 32768;
    unsigned short* We1T  = (unsigned short*)(wsf + off); off += 147456;
    unsigned short* We2T  = (unsigned short*)(wsf + off); off += 524288;
    unsigned short* Wf12T = (unsigned short*)(wsf + off); off += 131072;
    unsigned short* Wf22T = (unsigned short*)(wsf + off); off += 131072;

    hipMemsetAsync(prog, 0xFF, 64, stream);
    hipMemsetAsync(cnts, 0x00, 1024, stream);
    hipMemsetAsync(zacc, 0x00, 16384 * 4, stream);
    hipMemsetAsync(pts, 0x00, 48600 * 4, stream);
    hipMemsetAsync(out, 0x00, (size_t)out_size * 4, stream);
    preconv1_kernel<<<184, 256, 0, stream>>>(Wc1, Wc2, Wc3, We1, W1T, W2T, W3T, We1T);
    stage1_kernel<<<2056, 256, 0, stream>>>(pos, newp, prog, Wt, bt, W1T, W2T, W3T,
                                            bc1, bc2, bc3, encinh);
    tail_kernel<<<2120, 256, 0, stream>>>(We2, Wf12, Wf22, We2T, Wf12T, Wf22T,
                                          encinh, We1T, be1, e1h, be2, zacc, cnts,
                                          Wf11, bf11, Wf21, bf21, u1, u2,
                                          bf12, Wf13, bf13, bf22, Wf23, bf23, pts, out);
}

// Round 18
// 590.010 us; speedup vs baseline: 1.3401x; 1.3237x over previous
//
#include <hip/hip_runtime.h>
#include <math.h>

#define BATCH 8
#define NPTS 4096
#define SSAMP 256
#define KNBR 128
#define GGRID 2025

typedef __attribute__((ext_vector_type(8))) short bf16x8;
typedef __attribute__((ext_vector_type(8))) unsigned short u16x8;
typedef __attribute__((ext_vector_type(4))) float f32x4;
#define MFMA16(a, b, c) __builtin_amdgcn_mfma_f32_16x16x32_bf16((a), (b), (c), 0, 0, 0)

__device__ __forceinline__ float lrelu01(float v) { return v > 0.f ? v : 0.01f * v; }
__device__ __forceinline__ unsigned short f2bf(float f) {
    unsigned u = __float_as_uint(f);
    unsigned r = (u + 0x7FFFu + ((u >> 16) & 1u)) >> 16;
    return (unsigned short)r;
}
__device__ __forceinline__ unsigned long long umax64(unsigned long long a, unsigned long long b) {
    return a > b ? a : b;
}
__device__ __forceinline__ void spin_ge(const int* p, int target) {
    while (__hip_atomic_load(p, __ATOMIC_RELAXED, __HIP_MEMORY_SCOPE_AGENT) < target)
        __builtin_amdgcn_s_sleep(16);
}
__device__ __forceinline__ float aload(const float* p) {
    return __hip_atomic_load((float*)p, __ATOMIC_RELAXED, __HIP_MEMORY_SCOPE_AGENT);
}
__device__ __forceinline__ void astore(float* p, float v) {
    __hip_atomic_store(p, v, __ATOMIC_RELAXED, __HIP_MEMORY_SCOPE_AGENT);
}

// ---------------------------------------------------------------- 0) weight preconvert (We2T col-permuted)
__global__ void preconv_kernel(const float* __restrict__ Wc1, const float* __restrict__ Wc2,
                               const float* __restrict__ Wc3, const float* __restrict__ We1,
                               const float* __restrict__ We2, const float* __restrict__ Wf12,
                               const float* __restrict__ Wf22,
                               unsigned short* __restrict__ W1T, unsigned short* __restrict__ W2T,
                               unsigned short* __restrict__ W3T, unsigned short* __restrict__ We1T,
                               unsigned short* __restrict__ We2T, unsigned short* __restrict__ Wf12T,
                               unsigned short* __restrict__ Wf22T) {
    int o = blockIdx.x * 256 + threadIdx.x;
    const int S1 = 6144, S2 = 8192, S3 = 65536, S4 = 294912, S5 = 1048576, S6 = 262144;
    if (o < S1) { int n = o / 96, k = o - n * 96; W1T[o] = f2bf(k < 67 ? Wc1[k * 64 + n] : 0.f); return; }
    o -= S1;
    if (o < S2) { int n = o >> 6, k = o & 63; W2T[o] = f2bf(Wc2[k * 128 + n]); return; }
    o -= S2;
    if (o < S3) { int n = o >> 7, k = o & 127; W3T[o] = f2bf(Wc3[k * 512 + n]); return; }
    o -= S3;
    if (o < S4) { int n = o / 576, k = o - n * 576; We1T[o] = f2bf(k < 515 ? We1[k * 512 + n] : 0.f); return; }
    o -= S4;
    if (o < S5) {
        int np = o >> 9, k = o & 511;
        int src = (np & 1) ? 1024 + (np >> 1) : (np >> 1);
        We2T[o] = f2bf(We2[(size_t)k * 2048 + src]);
        return;
    }
    o -= S5;
    if (o < S6) { int n = o >> 9, k = o & 511; Wf12T[o] = f2bf(Wf12[k * 512 + n]); return; }
    o -= S6;
    { int n = o >> 9, k = o & 511; Wf22T[o] = f2bf(Wf22[k * 512 + n]); }
}

// ---------------------------------------------------------------- stage1: fps producers (blocks 0-7)
// + per-(b,s) consumers. Atomics-based handoff (R14-verified); no threadfence on serial paths.
__global__ void __launch_bounds__(256, 3) stage1_kernel(
    const float* __restrict__ pos, float* __restrict__ newpos, int* __restrict__ prog,
    const float* __restrict__ Wt, const float* __restrict__ bt,
    const unsigned short* __restrict__ W1T, const unsigned short* __restrict__ W2T,
    const unsigned short* __restrict__ W3T,
    const float* __restrict__ bc1, const float* __restrict__ bc2, const float* __restrict__ bc3,
    unsigned short* __restrict__ encin) {
    __shared__ __align__(16) unsigned char smem[53760];
    int blk = blockIdx.x, t = threadIdx.x;
    int wave = t >> 6, lane = t & 63;

    if (blk < 8) {
        float* pxs = (float*)smem;
        float* pys = (float*)(smem + 16384);
        float* pzs = (float*)(smem + 32768);
        float* npb = (float*)(smem + 49152);
        unsigned long long* rk = (unsigned long long*)(smem + 52224);
        int b = blk;
        const float* P = pos + (size_t)b * NPTS * 3;
        float* np = newpos + (size_t)b * SSAMP * 3;
        float px[16], py[16], pz[16], mind[16];
#pragma unroll
        for (int j = 0; j < 16; ++j) {
            int n = t + 256 * j;
            float X = P[n * 3 + 0], Y = P[n * 3 + 1], Z = P[n * 3 + 2];
            px[j] = X; py[j] = Y; pz[j] = Z;
            pxs[n] = X; pys[n] = Y; pzs[n] = Z;
            mind[j] = 3.402823466e+38f;
        }
        float cx = P[0], cy = P[1], cz = P[2];
        if (t == 0) { npb[0] = cx; npb[1] = cy; npb[2] = cz; }
        __syncthreads();
        for (int s = 1; s < SSAMP; ++s) {
            int p = s & 1;
            unsigned long long k[16];
#pragma unroll
            for (int j = 0; j < 16; ++j) {
                float dx = __fsub_rn(px[j], cx), dy = __fsub_rn(py[j], cy), dz = __fsub_rn(pz[j], cz);
                float d = __fadd_rn(__fadd_rn(__fmul_rn(dx, dx), __fmul_rn(dy, dy)), __fmul_rn(dz, dz));
                mind[j] = fminf(mind[j], d);
                k[j] = ((unsigned long long)__float_as_uint(mind[j]) << 32)
                     | (unsigned)~(unsigned)(t + 256 * j);
            }
#pragma unroll
            for (int st = 8; st > 0; st >>= 1)
#pragma unroll
                for (int j = 0; j < st; ++j) k[j] = umax64(k[j], k[j + st]);
            unsigned long long key = k[0];
            {
                unsigned long long a = __shfl_xor(key, 1, 64);
                unsigned long long b2 = __shfl_xor(key, 2, 64);
                unsigned long long c = __shfl_xor(key, 3, 64);
                key = umax64(umax64(key, a), umax64(b2, c));
                a = __shfl_xor(key, 4, 64);
                b2 = __shfl_xor(key, 8, 64);
                c = __shfl_xor(key, 12, 64);
                key = umax64(umax64(key, a), umax64(b2, c));
                a = __shfl_xor(key, 16, 64);
                b2 = __shfl_xor(key, 32, 64);
                c = __shfl_xor(key, 48, 64);
                key = umax64(umax64(key, a), umax64(b2, c));
            }
            if (lane == 0) rk[p * 4 + wave] = key;
            __syncthreads();
            unsigned long long k0 = rk[p * 4 + 0], k1 = rk[p * 4 + 1];
            unsigned long long k2 = rk[p * 4 + 2], k3 = rk[p * 4 + 3];
            unsigned long long bk = umax64(umax64(k0, k1), umax64(k2, k3));
            int nx = (int)(~(unsigned)(bk & 0xFFFFFFFFull));
            cx = pxs[nx]; cy = pys[nx]; cz = pzs[nx];
            if (t == 0) {
                npb[s * 3 + 0] = cx;
                npb[s * 3 + 1] = cy;
                npb[s * 3 + 2] = cz;
            }
            if ((s & 7) == 7) {
                if (t < 24) astore(&np[(s - 7) * 3 + t], npb[(s - 7) * 3 + t]);
                if (t == 0 && s >= 15)
                    __hip_atomic_store(&prog[b], s - 8, __ATOMIC_RELAXED, __HIP_MEMORY_SCOPE_AGENT);
            }
        }
        __syncthreads();
        if (t == 0)
            __hip_atomic_store(&prog[b], 255, __ATOMIC_RELAXED, __HIP_MEMORY_SCOPE_AGENT);
        return;
    }

    unsigned short* featl = (unsigned short*)smem;
    unsigned short* h2    = (unsigned short*)smem;
    unsigned short* h1    = (unsigned short*)(smem + 34816);
    float* mred = (float*)(smem + 34816);
    int*   vld  = (int*)(smem + 53248);
    int*   wl   = (int*)smem;
    int*   cnt  = (int*)(smem + 2048);
    float* wtb  = (float*)(smem + 26624);

    int cons = blk - 8;
    int s = cons >> 3, b = cons & 7;
    int bs = b * 256 + s;
    int quad = lane >> 4, l16 = lane & 15;

    if (t == 0) spin_ge(&prog[b], s);
    __syncthreads();
    float q0 = aload(&newpos[(size_t)bs * 3 + 0]);
    float q1 = aload(&newpos[(size_t)bs * 3 + 1]);
    float q2 = aload(&newpos[(size_t)bs * 3 + 2]);

    const float* P = pos + (size_t)b * NPTS * 3;
    {
        int base = 0;
        for (int c = 0; c < 16 && base < KNBR; ++c) {
            int n = wave * 1024 + c * 64 + lane;
            float dx = __fsub_rn(P[n * 3 + 0], q0);
            float dy = __fsub_rn(P[n * 3 + 1], q1);
            float dz = __fsub_rn(P[n * 3 + 2], q2);
            float d2 = __fadd_rn(__fadd_rn(__fmul_rn(dx, dx), __fmul_rn(dy, dy)), __fmul_rn(dz, dz));
            bool in = (d2 <= 0.04f);
            unsigned long long mask = __ballot(in);
            if (in) {
                int p = base + __popcll(mask & ((1ull << lane) - 1ull));
                if (p < KNBR) wl[wave * 128 + p] = n;
            }
            base += __popcll(mask);
        }
        if (lane == 0) cnt[wave] = base < KNBR ? base : KNBR;
    }
    __syncthreads();
    {
        int c0 = cnt[0], c1 = cnt[1], c2 = cnt[2], c3 = cnt[3];
        if (t < 128) {
            int idx = -1, r = t;
            if (r < c0) idx = wl[r];
            else {
                r -= c0;
                if (r < c1) idx = wl[128 + r];
                else {
                    r -= c1;
                    if (r < c2) idx = wl[256 + r];
                    else { r -= c2; if (r < c3) idx = wl[384 + r]; }
                }
            }
            vld[t] = idx;
        }
        if (t < 192) wtb[t] = Wt[t];
        else wtb[t] = bt[t - 192];
    }
    __syncthreads();

    int vbits = 0;
#pragma unroll
    for (int i = 0; i < 2; ++i)
#pragma unroll
        for (int reg = 0; reg < 4; ++reg)
            if (vld[(2 * wave + i) * 16 + quad * 4 + reg] >= 0) vbits |= 1 << (i * 4 + reg);

    {
        int sr = t >> 1, sh = t & 1;
        int n = vld[sr];
        int ns = n < 0 ? 0 : n;
        const float* pp = pos + ((size_t)b * NPTS + ns) * 3;
        float p0 = pp[0], p1 = pp[1], p2 = pp[2];
        unsigned short* frow = &featl[sr * 104];
        u16x8 z8 = {0, 0, 0, 0, 0, 0, 0, 0};
        if (n >= 0) {
#pragma unroll
            for (int g = 0; g < 4; ++g) {
                u16x8 v8;
#pragma unroll
                for (int e = 0; e < 8; ++e) {
                    int c = sh * 32 + g * 8 + e;
                    float v = fmaf(p2, wtb[128 + c], fmaf(p1, wtb[64 + c], fmaf(p0, wtb[c], wtb[192 + c])));
                    v8[e] = (unsigned short)f2bf(lrelu01(v));
                }
                *(u16x8*)&frow[sh * 32 + g * 8] = v8;
            }
        } else {
#pragma unroll
            for (int g = 0; g < 4; ++g) *(u16x8*)&frow[sh * 32 + g * 8] = z8;
        }
        if (sh == 1) {
            u16x8 dv = z8;
            if (n >= 0) {
                dv[0] = (unsigned short)f2bf(__fsub_rn(p0, q0));
                dv[1] = (unsigned short)f2bf(__fsub_rn(p1, q1));
                dv[2] = (unsigned short)f2bf(__fsub_rn(p2, q2));
            }
            *(u16x8*)&frow[64] = dv;
            *(u16x8*)&frow[72] = z8;
            *(u16x8*)&frow[80] = z8;
            *(u16x8*)&frow[88] = z8;
        }
    }
    __syncthreads();

    {
        f32x4 acc[2][4];
#pragma unroll
        for (int i = 0; i < 2; ++i)
#pragma unroll
            for (int nt = 0; nt < 4; ++nt) acc[i][nt] = (f32x4){0.f, 0.f, 0.f, 0.f};
#pragma unroll
        for (int ks = 0; ks < 3; ++ks) {
            bf16x8 afr[2];
#pragma unroll
            for (int i = 0; i < 2; ++i)
                afr[i] = *(const bf16x8*)&featl[((2 * wave + i) * 16 + l16) * 104 + ks * 32 + quad * 8];
#pragma unroll
            for (int nt = 0; nt < 4; ++nt) {
                bf16x8 bfr = *(const bf16x8*)(W1T + (nt * 16 + l16) * 96 + ks * 32 + quad * 8);
                acc[0][nt] = MFMA16(afr[0], bfr, acc[0][nt]);
                acc[1][nt] = MFMA16(afr[1], bfr, acc[1][nt]);
            }
        }
#pragma unroll
        for (int i = 0; i < 2; ++i)
#pragma unroll
            for (int nt = 0; nt < 4; ++nt) {
                int col = nt * 16 + l16;
                float bias = bc1[col];
#pragma unroll
                for (int reg = 0; reg < 4; ++reg) {
                    int row = (2 * wave + i) * 16 + quad * 4 + reg;
                    h1[row * 72 + col] = f2bf(lrelu01(acc[i][nt][reg] + bias));
                }
            }
    }
    __syncthreads();

    {
        f32x4 acc[2][8];
#pragma unroll
        for (int i = 0; i < 2; ++i)
#pragma unroll
            for (int nt = 0; nt < 8; ++nt) acc[i][nt] = (f32x4){0.f, 0.f, 0.f, 0.f};
#pragma unroll
        for (int ks = 0; ks < 2; ++ks) {
            bf16x8 afr[2];
#pragma unroll
            for (int i = 0; i < 2; ++i)
                afr[i] = *(const bf16x8*)&h1[((2 * wave + i) * 16 + l16) * 72 + ks * 32 + quad * 8];
#pragma unroll
            for (int nt = 0; nt < 8; ++nt) {
                bf16x8 bfr = *(const bf16x8*)(W2T + (nt * 16 + l16) * 64 + ks * 32 + quad * 8);
                acc[0][nt] = MFMA16(afr[0], bfr, acc[0][nt]);
                acc[1][nt] = MFMA16(afr[1], bfr, acc[1][nt]);
            }
        }
        __syncthreads();
#pragma unroll
        for (int i = 0; i < 2; ++i)
#pragma unroll
            for (int nt = 0; nt < 8; ++nt) {
                int col = nt * 16 + l16;
                float bias = bc2[col];
#pragma unroll
                for (int reg = 0; reg < 4; ++reg) {
                    int row = (2 * wave + i) * 16 + quad * 4 + reg;
                    h2[row * 136 + col] = f2bf(lrelu01(acc[i][nt][reg] + bias));
                }
            }
    }
    __syncthreads();

    for (int c3 = 0; c3 < 4; ++c3) {
        f32x4 acc[2][8];
#pragma unroll
        for (int i = 0; i < 2; ++i)
#pragma unroll
            for (int nt = 0; nt < 8; ++nt) acc[i][nt] = (f32x4){0.f, 0.f, 0.f, 0.f};
#pragma unroll
        for (int ks = 0; ks < 4; ++ks) {
            bf16x8 afr[2];
#pragma unroll
            for (int i = 0; i < 2; ++i)
                afr[i] = *(const bf16x8*)&h2[((2 * wave + i) * 16 + l16) * 136 + ks * 32 + quad * 8];
#pragma unroll
            for (int nt = 0; nt < 8; ++nt) {
                bf16x8 bfr = *(const bf16x8*)(W3T + ((size_t)((c3 * 8 + nt) * 16 + l16)) * 128 + ks * 32 + quad * 8);
                acc[0][nt] = MFMA16(afr[0], bfr, acc[0][nt]);
                acc[1][nt] = MFMA16(afr[1], bfr, acc[1][nt]);
            }
        }
#pragma unroll
        for (int nt = 0; nt < 8; ++nt) {
            float vmax = -3.402823466e+38f;
#pragma unroll
            for (int i = 0; i < 2; ++i)
#pragma unroll
                for (int reg = 0; reg < 4; ++reg)
                    if (vbits & (1 << (i * 4 + reg))) vmax = fmaxf(vmax, acc[i][nt][reg]);
            vmax = fmaxf(vmax, __shfl_xor(vmax, 16));
            vmax = fmaxf(vmax, __shfl_xor(vmax, 32));
            if (lane < 16) mred[wave * 512 + (c3 * 8 + nt) * 16 + l16] = vmax;
        }
    }
    __syncthreads();
    unsigned short* erow = encin + (size_t)bs * 576;
    for (int c = t; c < 576; c += 256) {
        unsigned short v;
        if (c < 512) {
            float m4 = fmaxf(fmaxf(mred[c], mred[512 + c]), fmaxf(mred[1024 + c], mred[1536 + c]));
            v = f2bf(lrelu01(m4 + bc3[c]));
        } else if (c < 515) {
            v = f2bf(c == 512 ? q0 : (c == 513 ? q1 : q2));
        } else v = 0;
        erow[c] = v;
    }
}

// ---------------------------------------------------------------- tail: one kernel, 1352 blocks (R14).
// [0,64) e1 -> cnts[rb]; [64,320) e2v -> cnts[16]; [320,336) ukern -> cnts[17]/[18];
// [336,844) ff1 (j,cc) -> pts atomics + cnts[20+j]; [844,1352) ff2 -> out atomics.
// ff blocks preload all static LDS BEFORE spinning (shortens post-release latency).
__global__ void __launch_bounds__(256, 2) tail_kernel(
    const unsigned short* __restrict__ encinh, const unsigned short* __restrict__ We1T,
    const float* __restrict__ be1, unsigned short* __restrict__ e1h,
    const unsigned short* __restrict__ We2T, const float* __restrict__ be2,
    float* __restrict__ zacc, int* __restrict__ cnts,
    const float* __restrict__ Wf11, const float* __restrict__ bf11,
    const float* __restrict__ Wf21, const float* __restrict__ bf21,
    float* __restrict__ u1, float* __restrict__ u2,
    const unsigned short* __restrict__ Wf12T, const float* __restrict__ bf12,
    const float* __restrict__ Wf13, const float* __restrict__ bf13,
    const unsigned short* __restrict__ Wf22T, const float* __restrict__ bf22,
    const float* __restrict__ Wf23, const float* __restrict__ bf23,
    float* __restrict__ pts, float* __restrict__ outv) {
    __shared__ __align__(16) unsigned char smem[40960];
    int blk = blockIdx.x, t = threadIdx.x;
    int wave = t >> 6, lane = t & 63, quad = lane >> 4, l16 = lane & 15;

    if (blk < 320) {
        unsigned short* As = (unsigned short*)smem;
        bool is_e1 = blk < 64;
        int rb, cb;
        const unsigned short* A;
        const unsigned short* BT;
        int Ka;
        if (is_e1) { rb = blk >> 2; cb = blk & 3; A = encinh; BT = We1T; Ka = 576; }
        else {
            int j = blk - 64; rb = j >> 4; cb = j & 15; A = e1h; BT = We2T; Ka = 512;
            if (t == 0) spin_ge(&cnts[rb], 4);
            __syncthreads();
            __threadfence();   // acquire e1h (bulk normal stores)
        }
        int row0 = rb * 128, col0 = cb * 128;
        f32x4 acc[2][8];
#pragma unroll
        for (int i = 0; i < 2; ++i)
#pragma unroll
            for (int nt = 0; nt < 8; ++nt) acc[i][nt] = (f32x4){0.f, 0.f, 0.f, 0.f};
        int nk = Ka >> 6;
        int sr = t >> 1, sh = t & 1;
        const unsigned short* Arow = A + (size_t)(row0 + sr) * Ka + sh * 32;
        for (int ks = 0; ks < nk; ++ks) {
            u16x8 av[4];
#pragma unroll
            for (int j = 0; j < 4; ++j) av[j] = *(const u16x8*)(Arow + ks * 64 + j * 8);
            __syncthreads();
#pragma unroll
            for (int j = 0; j < 4; ++j) *(u16x8*)&As[sr * 72 + sh * 32 + j * 8] = av[j];
            __syncthreads();
#pragma unroll
            for (int ks2 = 0; ks2 < 2; ++ks2) {
                bf16x8 afr0 = *(const bf16x8*)&As[((2 * wave) * 16 + l16) * 72 + ks2 * 32 + quad * 8];
                bf16x8 afr1 = *(const bf16x8*)&As[((2 * wave + 1) * 16 + l16) * 72 + ks2 * 32 + quad * 8];
#pragma unroll
                for (int nt = 0; nt < 8; ++nt) {
                    bf16x8 bfr = *(const bf16x8*)(BT + (size_t)(col0 + nt * 16 + l16) * Ka + ks * 64 + ks2 * 32 + quad * 8);
                    acc[0][nt] = MFMA16(afr0, bfr, acc[0][nt]);
                    acc[1][nt] = MFMA16(afr1, bfr, acc[1][nt]);
                }
            }
        }
        if (is_e1) {
#pragma unroll
            for (int i = 0; i < 2; ++i)
#pragma unroll
                for (int nt = 0; nt < 8; ++nt) {
                    int col = col0 + nt * 16 + l16;
                    float bv = be1[col];
#pragma unroll
                    for (int reg = 0; reg < 4; ++reg) {
                        int row = row0 + (2 * wave + i) * 16 + quad * 4 + reg;
                        e1h[(size_t)row * 512 + col] = f2bf(lrelu01(acc[i][nt][reg] + bv));
                    }
                }
            __syncthreads();
            if (t == 0) { __threadfence(); atomicAdd(&cnts[rb], 1); }
        } else {
            int b = row0 >> 8;
#pragma unroll
            for (int nt = 0; nt < 8; ++nt) {
                int colp = col0 + nt * 16 + l16;
                int c2 = colp >> 1;
                int srcc = (colp & 1) ? 1024 + c2 : c2;
                float bv = be2[srcc];
                float num = 0.f, den = 0.f;
#pragma unroll
                for (int i = 0; i < 2; ++i)
#pragma unroll
                    for (int reg = 0; reg < 4; ++reg) {
                        float val = acc[i][nt][reg] + bv;
                        float par = __shfl_xor(val, 1, 64);
                        float d = expf(-0.5f * par);
                        num += val * d;
                        den += d;
                    }
                num += __shfl_xor(num, 16, 64); den += __shfl_xor(den, 16, 64);
                num += __shfl_xor(num, 32, 64); den += __shfl_xor(den, 32, 64);
                if (quad == 0 && !(l16 & 1)) {
                    atomicAdd(&zacc[((b << 10) + c2) * 2 + 0], num);
                    atomicAdd(&zacc[((b << 10) + c2) * 2 + 1], den);
                }
            }
            __syncthreads();
            if (t == 0) atomicAdd(&cnts[16], 1);
        }
        return;
    }

    if (blk < 336) {
        // ---------- ukern ----------
        float* zt = (float*)smem;
        float* red = (float*)(smem + 32768);
        int j = blk - 320;
        int dec = j >> 3, cb = j & 7;
        const float* W = dec ? Wf21 : Wf11;
        const float* bias = dec ? bf21 : bf11;
        float* u = dec ? u2 : u1;
        if (t == 0) spin_ge(&cnts[16], 256);
        __syncthreads();
#pragma unroll
        for (int i = 0; i < 32; ++i) {
            int o = t + i * 256;
            float num = aload(&zacc[o * 2 + 0]);
            float den = aload(&zacc[o * 2 + 1]);
            zt[(o & 1023) * 8 + (o >> 10)] = num / den;
        }
        __syncthreads();
        int c64 = t & 63, kc = t >> 6;
        int co = cb * 64 + c64;
        float acc[8];
#pragma unroll
        for (int r = 0; r < 8; ++r) acc[r] = 0.f;
        for (int i = 0; i < 256; ++i) {
            int ci = kc * 256 + i;
            float w = W[(size_t)ci * 512 + co];
            const float4* zp = (const float4*)&zt[ci * 8];
            float4 z0 = zp[0], z1 = zp[1];
            acc[0] = fmaf(z0.x, w, acc[0]); acc[1] = fmaf(z0.y, w, acc[1]);
            acc[2] = fmaf(z0.z, w, acc[2]); acc[3] = fmaf(z0.w, w, acc[3]);
            acc[4] = fmaf(z1.x, w, acc[4]); acc[5] = fmaf(z1.y, w, acc[5]);
            acc[6] = fmaf(z1.z, w, acc[6]); acc[7] = fmaf(z1.w, w, acc[7]);
        }
#pragma unroll
        for (int r = 0; r < 8; ++r) red[(kc * 64 + c64) * 8 + r] = acc[r];
        __syncthreads();
        if (kc == 0) {
#pragma unroll
            for (int r = 0; r < 8; ++r) {
                float v = red[(0 * 64 + c64) * 8 + r] + red[(1 * 64 + c64) * 8 + r]
                        + red[(2 * 64 + c64) * 8 + r] + red[(3 * 64 + c64) * 8 + r] + bias[co];
                astore(&u[r * 512 + co], v);
            }
        }
        __syncthreads();
        if (t == 0) atomicAdd(&cnts[17 + dec], 1);
        return;
    }

    // ---------- foldfuse, (j, cc)-split: ff1 336..844, ff2 844..1352 ----------
    {
        unsigned short* As = (unsigned short*)smem;          // 18432
        float* sW = (float*)(smem + 18432);                  // [3][512]
        float* sU = (float*)(smem + 24576);                  // [2][512]
        float* sP = (float*)(smem + 28672);                  // [128*3]
        float* sB = (float*)(smem + 30208);                  // [128]
        float* sRC = (float*)(smem + 30720);                 // [128][4]
        int dec = blk < 844 ? 0 : 1;
        int idx0 = blk - (dec ? 844 : 336);
        int j = idx0 >> 2, cc = idx0 & 3;
        const float* u = dec ? u2 : u1;
        const float* Wfold = dec ? Wf21 : Wf11;
        int nExtra = dec ? 3 : 2;
        const unsigned short* WT = dec ? Wf22T : Wf12T;
        const float* bmid = dec ? bf22 : bf12;
        const float* wout = dec ? Wf23 : Wf13;
        const float* bout = dec ? bf23 : bf13;
        float* ov = dec ? outv : pts;
        int row0 = j * 128, col0 = cc * 128;
        int b0 = row0 / 2025;

        // static preloads BEFORE the spin (inputs only -> safe, hides post-release latency)
        for (int idx = t; idx < 1536; idx += 256) {
            int r = idx >> 9, c = idx & 511;
            sW[r * 512 + c] = (r < nExtra) ? Wfold[(size_t)(1024 + r) * 512 + c] : 0.f;
        }
        for (int idx = t; idx < 384; idx += 256) sP[idx] = wout[col0 * 3 + idx];
        if (t < 128) sB[t] = bmid[col0 + t];
        if (dec == 0 && t < 128) {
            int rg = row0 + t; if (rg > 16199) rg = 16199;
            int b = rg / 2025, g = rg - b * 2025;
            int i = g / 45, jj = g - i * 45;
            sRC[t * 4 + 0] = (jj == 44) ? 0.3f : (float)(-0.3 + jj * (0.6 / 44.0));
            sRC[t * 4 + 1] = (i == 44) ? 0.3f : (float)(-0.3 + i * (0.6 / 44.0));
            sRC[t * 4 + 2] = 0.f;
            sRC[t * 4 + 3] = __int_as_float(b - b0);
        }

        if (t == 0) {
            spin_ge(&cnts[17 + dec], 8);
            if (dec) spin_ge(&cnts[20 + j], 4);
        }
        __syncthreads();

        for (int idx = t; idx < 1024; idx += 256) {
            int rb = idx >> 9;
            int bb = b0 + rb; if (bb > 7) bb = 7;
            sU[rb * 512 + (idx & 511)] = aload(&u[bb * 512 + (idx & 511)]);
        }
        if (dec == 1 && t < 128) {
            int rg = row0 + t; if (rg > 16199) rg = 16199;
            int b = rg / 2025;
            sRC[t * 4 + 0] = aload(&pts[rg * 3 + 0]);
            sRC[t * 4 + 1] = aload(&pts[rg * 3 + 1]);
            sRC[t * 4 + 2] = aload(&pts[rg * 3 + 2]);
            sRC[t * 4 + 3] = __int_as_float(b - b0);
        }
        __syncthreads();

        float proj[2][4][3];
#pragma unroll
        for (int i = 0; i < 2; ++i)
#pragma unroll
            for (int r = 0; r < 4; ++r) { proj[i][r][0] = 0.f; proj[i][r][1] = 0.f; proj[i][r][2] = 0.f; }

        int sr = t >> 1, sh = t & 1;
        float4 rc = *(const float4*)&sRC[sr * 4];
        int ubi = __float_as_int(rc.w);
        const float* up = sU + ubi * 512;
        f32x4 acc[2][8];
#pragma unroll
        for (int i = 0; i < 2; ++i)
#pragma unroll
            for (int nt = 0; nt < 8; ++nt) acc[i][nt] = (f32x4){0.f, 0.f, 0.f, 0.f};
        for (int ks = 0; ks < 8; ++ks) {
            __syncthreads();
            {
                int cbase = ks * 64 + sh * 32;
                const float4* w0p = (const float4*)&sW[cbase];
                const float4* w1p = (const float4*)&sW[512 + cbase];
                const float4* w2p = (const float4*)&sW[1024 + cbase];
                const float4* uup = (const float4*)&up[cbase];
#pragma unroll
                for (int g4 = 0; g4 < 8; ++g4) {
                    float4 w0 = w0p[g4], w1 = w1p[g4], w2 = w2p[g4], uu = uup[g4];
                    float v0 = fmaf(rc.z, w2.x, fmaf(rc.y, w1.x, fmaf(rc.x, w0.x, uu.x)));
                    float v1 = fmaf(rc.z, w2.y, fmaf(rc.y, w1.y, fmaf(rc.x, w0.y, uu.y)));
                    float v2 = fmaf(rc.z, w2.z, fmaf(rc.y, w1.z, fmaf(rc.x, w0.z, uu.z)));
                    float v3 = fmaf(rc.z, w2.w, fmaf(rc.y, w1.w, fmaf(rc.x, w0.w, uu.w)));
                    uint2 pk;
                    pk.x = (unsigned)f2bf(fmaxf(v0, 0.f)) | ((unsigned)f2bf(fmaxf(v1, 0.f)) << 16);
                    pk.y = (unsigned)f2bf(fmaxf(v2, 0.f)) | ((unsigned)f2bf(fmaxf(v3, 0.f)) << 16);
                    *(uint2*)&As[sr * 72 + sh * 32 + g4 * 4] = pk;
                }
            }
            __syncthreads();
#pragma unroll
            for (int ks2 = 0; ks2 < 2; ++ks2) {
                bf16x8 afr0 = *(const bf16x8*)&As[((2 * wave) * 16 + l16) * 72 + ks2 * 32 + quad * 8];
                bf16x8 afr1 = *(const bf16x8*)&As[((2 * wave + 1) * 16 + l16) * 72 + ks2 * 32 + quad * 8];
#pragma unroll
                for (int nt = 0; nt < 8; ++nt) {
                    bf16x8 bfr = *(const bf16x8*)(WT + (size_t)(col0 + nt * 16 + l16) * 512 + ks * 64 + ks2 * 32 + quad * 8);
                    acc[0][nt] = MFMA16(afr0, bfr, acc[0][nt]);
                    acc[1][nt] = MFMA16(afr1, bfr, acc[1][nt]);
                }
            }
        }
#pragma unroll
        for (int i = 0; i < 2; ++i)
#pragma unroll
            for (int nt = 0; nt < 8; ++nt) {
                int lc = nt * 16 + l16;
                float bv = sB[lc];
                float w0 = sP[lc * 3 + 0], w1 = sP[lc * 3 + 1], w2 = sP[lc * 3 + 2];
#pragma unroll
                for (int reg = 0; reg < 4; ++reg) {
                    float h = fmaxf(acc[i][nt][reg] + bv, 0.f);
                    proj[i][reg][0] = fmaf(h, w0, proj[i][reg][0]);
                    proj[i][reg][1] = fmaf(h, w1, proj[i][reg][1]);
                    proj[i][reg][2] = fmaf(h, w2, proj[i][reg][2]);
                }
            }
        float o0 = (cc == 0) ? bout[0] : 0.f;
        float o1 = (cc == 0) ? bout[1] : 0.f;
        float o2 = (cc == 0) ? bout[2] : 0.f;
#pragma unroll
        for (int i = 0; i < 2; ++i)
#pragma unroll
            for (int reg = 0; reg < 4; ++reg) {
                float p0 = proj[i][reg][0], p1 = proj[i][reg][1], p2 = proj[i][reg][2];
#pragma unroll
                for (int m = 1; m < 16; m <<= 1) {
                    p0 += __shfl_xor(p0, m, 64);
                    p1 += __shfl_xor(p1, m, 64);
                    p2 += __shfl_xor(p2, m, 64);
                }
                if (l16 == 0) {
                    int row = row0 + (2 * wave + i) * 16 + quad * 4 + reg;
                    if (row < 16200) {
                        atomicAdd(&ov[row * 3 + 0], p0 + o0);
                        atomicAdd(&ov[row * 3 + 1], p1 + o1);
                        atomicAdd(&ov[row * 3 + 2], p2 + o2);
                    }
                }
            }
        if (dec == 0) {
            __syncthreads();
            if (t == 0) atomicAdd(&cnts[20 + j], 1);
        }
    }
}

extern "C" void kernel_launch(void* const* d_in, const int* in_sizes, int n_in,
                              void* d_out, int out_size, void* d_ws, size_t ws_size,
                              hipStream_t stream) {
    const float* pos  = (const float*)d_in[0];
    const float* Wt   = (const float*)d_in[1];
    const float* bt   = (const float*)d_in[2];
    const float* Wc1  = (const float*)d_in[3];
    const float* bc1  = (const float*)d_in[4];
    const float* Wc2  = (const float*)d_in[5];
    const float* bc2  = (const float*)d_in[6];
    const float* Wc3  = (const float*)d_in[7];
    const float* bc3  = (const float*)d_in[8];
    const float* We1  = (const float*)d_in[9];
    const float* be1  = (const float*)d_in[10];
    const float* We2  = (const float*)d_in[11];
    const float* be2  = (const float*)d_in[12];
    const float* Wf11 = (const float*)d_in[13];
    const float* bf11 = (const float*)d_in[14];
    const float* Wf12 = (const float*)d_in[15];
    const float* bf12 = (const float*)d_in[16];
    const float* Wf13 = (const float*)d_in[17];
    const float* bf13 = (const float*)d_in[18];
    const float* Wf21 = (const float*)d_in[19];
    const float* bf21 = (const float*)d_in[20];
    const float* Wf22 = (const float*)d_in[21];
    const float* bf22 = (const float*)d_in[22];
    const float* Wf23 = (const float*)d_in[23];
    const float* bf23 = (const float*)d_in[24];
    float* out = (float*)d_out;

    float* wsf = (float*)d_ws;
    size_t off = 0;
    unsigned short* encinh= (unsigned short*)(wsf + off); off += 589824;   // [2048][576] bf16
    unsigned short* e1h   = (unsigned short*)(wsf + off); off += 524288;   // [2048][512] bf16
    float* zacc = wsf + off; off += 16384;     // [8][1024][2]
    float* u1   = wsf + off; off += 4096;
    float* u2   = wsf + off; off += 4096;
    float* pts  = wsf + off; off += 48600;     // [16200][3] (atomic-accumulated)
    float* newp = wsf + off; off += 6144;      // [B,S,3]
    int*   prog = (int*)(wsf + off); off += 16;
    int*   cnts = (int*)(wsf + off); off += 256;
    unsigned short* W1T   = (unsigned short*)(wsf + off); off += 3072;
    unsigned short* W2T   = (unsigned short*)(wsf + off); off += 4096;
    unsigned short* W3T   = (unsigned short*)(wsf + off); off += 32768;
    unsigned short* We1T  = (unsigned short*)(wsf + off); off += 147456;
    unsigned short* We2T  = (unsigned short*)(wsf + off); off += 524288;
    unsigned short* Wf12T = (unsigned short*)(wsf + off); off += 131072;
    unsigned short* Wf22T = (unsigned short*)(wsf + off); off += 131072;

    hipMemsetAsync(prog, 0xFF, 64, stream);
    hipMemsetAsync(cnts, 0x00, 1024, stream);
    hipMemsetAsync(zacc, 0x00, 16384 * 4, stream);
    hipMemsetAsync(pts, 0x00, 48600 * 4, stream);
    hipMemsetAsync(out, 0x00, (size_t)out_size * 4, stream);
    preconv_kernel<<<7608, 256, 0, stream>>>(Wc1, Wc2, Wc3, We1, We2, Wf12, Wf22,
                                             W1T, W2T, W3T, We1T, We2T, Wf12T, Wf22T);
    stage1_kernel<<<2056, 256, 0, stream>>>(pos, newp, prog, Wt, bt, W1T, W2T, W3T,
                                            bc1, bc2, bc3, encinh);
    tail_kernel<<<1352, 256, 0, stream>>>(encinh, We1T, be1, e1h, We2T, be2, zacc, cnts,
                                          Wf11, bf11, Wf21, bf21, u1, u2,
                                          Wf12T, bf12, Wf13, bf13,
                                          Wf22T, bf22, Wf23, bf23, pts, out);
}

// Round 19
// 583.374 us; speedup vs baseline: 1.3553x; 1.0114x over previous
//
#include <hip/hip_runtime.h>
#include <math.h>

#define BATCH 8
#define NPTS 4096
#define SSAMP 256
#define KNBR 128
#define GGRID 2025

typedef __attribute__((ext_vector_type(8))) short bf16x8;
typedef __attribute__((ext_vector_type(8))) unsigned short u16x8;
typedef __attribute__((ext_vector_type(4))) float f32x4;
#define MFMA16(a, b, c) __builtin_amdgcn_mfma_f32_16x16x32_bf16((a), (b), (c), 0, 0, 0)

__device__ __forceinline__ float lrelu01(float v) { return v > 0.f ? v : 0.01f * v; }
__device__ __forceinline__ unsigned short f2bf(float f) {
    unsigned u = __float_as_uint(f);
    unsigned r = (u + 0x7FFFu + ((u >> 16) & 1u)) >> 16;
    return (unsigned short)r;
}
__device__ __forceinline__ unsigned long long umax64(unsigned long long a, unsigned long long b) {
    return a > b ? a : b;
}
__device__ __forceinline__ void spin_ge(const int* p, int target) {
    while (__hip_atomic_load(p, __ATOMIC_RELAXED, __HIP_MEMORY_SCOPE_AGENT) < target)
        __builtin_amdgcn_s_sleep(16);
}
__device__ __forceinline__ float aload(const float* p) {
    return __hip_atomic_load((float*)p, __ATOMIC_RELAXED, __HIP_MEMORY_SCOPE_AGENT);
}
__device__ __forceinline__ void astore(float* p, float v) {
    __hip_atomic_store(p, v, __ATOMIC_RELAXED, __HIP_MEMORY_SCOPE_AGENT);
}

// ---------------------------------------------------------------- 0) weight preconvert (We2T col-permuted)
__global__ void preconv_kernel(const float* __restrict__ Wc1, const float* __restrict__ Wc2,
                               const float* __restrict__ Wc3, const float* __restrict__ We1,
                               const float* __restrict__ We2, const float* __restrict__ Wf12,
                               const float* __restrict__ Wf22,
                               unsigned short* __restrict__ W1T, unsigned short* __restrict__ W2T,
                               unsigned short* __restrict__ W3T, unsigned short* __restrict__ We1T,
                               unsigned short* __restrict__ We2T, unsigned short* __restrict__ Wf12T,
                               unsigned short* __restrict__ Wf22T) {
    int o = blockIdx.x * 256 + threadIdx.x;
    const int S1 = 6144, S2 = 8192, S3 = 65536, S4 = 294912, S5 = 1048576, S6 = 262144;
    if (o < S1) { int n = o / 96, k = o - n * 96; W1T[o] = f2bf(k < 67 ? Wc1[k * 64 + n] : 0.f); return; }
    o -= S1;
    if (o < S2) { int n = o >> 6, k = o & 63; W2T[o] = f2bf(Wc2[k * 128 + n]); return; }
    o -= S2;
    if (o < S3) { int n = o >> 7, k = o & 127; W3T[o] = f2bf(Wc3[k * 512 + n]); return; }
    o -= S3;
    if (o < S4) { int n = o / 576, k = o - n * 576; We1T[o] = f2bf(k < 515 ? We1[k * 512 + n] : 0.f); return; }
    o -= S4;
    if (o < S5) {
        int np = o >> 9, k = o & 511;
        int src = (np & 1) ? 1024 + (np >> 1) : (np >> 1);
        We2T[o] = f2bf(We2[(size_t)k * 2048 + src]);
        return;
    }
    o -= S5;
    if (o < S6) { int n = o >> 9, k = o & 511; Wf12T[o] = f2bf(Wf12[k * 512 + n]); return; }
    o -= S6;
    { int n = o >> 9, k = o & 511; Wf22T[o] = f2bf(Wf22[k * 512 + n]); }
}

// ---------------------------------------------------------------- stage1 (2392 blocks):
//  [0,8)        fps -> prog[b]
//  [8,2056)     pc consumers -> encin + cnts[150+rb] (fence+atomic release)
//  [2056,2120)  e1 (waits cnts[150+rb]==128) -> e1h + cnts[rb]
//  [2120,2376)  e2v (waits cnts[rb]==4) -> zacc atomics + cnts[16]
//  [2376,2392)  ukern (waits cnts[16]==256) -> u1/u2 via astore
// Appended blocks dispatch only as consumers retire -> fill fps-shadow slots (anti-R16).
__global__ void __launch_bounds__(256, 3) stage1_kernel(
    const float* __restrict__ pos, float* __restrict__ newpos, int* __restrict__ prog,
    int* __restrict__ cnts,
    const float* __restrict__ Wt, const float* __restrict__ bt,
    const unsigned short* __restrict__ W1T, const unsigned short* __restrict__ W2T,
    const unsigned short* __restrict__ W3T,
    const float* __restrict__ bc1, const float* __restrict__ bc2, const float* __restrict__ bc3,
    unsigned short* __restrict__ encin,
    const unsigned short* __restrict__ We1T, const float* __restrict__ be1,
    unsigned short* __restrict__ e1h,
    const unsigned short* __restrict__ We2T, const float* __restrict__ be2,
    float* __restrict__ zacc,
    const float* __restrict__ Wf11, const float* __restrict__ bf11,
    const float* __restrict__ Wf21, const float* __restrict__ bf21,
    float* __restrict__ u1, float* __restrict__ u2) {
    __shared__ __align__(16) unsigned char smem[53760];
    int blk = blockIdx.x, t = threadIdx.x;
    int wave = t >> 6, lane = t & 63;
    int quad = lane >> 4, l16 = lane & 15;

    if (blk < 8) {
        // ================= FPS producer (R14-verified) =================
        float* pxs = (float*)smem;
        float* pys = (float*)(smem + 16384);
        float* pzs = (float*)(smem + 32768);
        float* npb = (float*)(smem + 49152);
        unsigned long long* rk = (unsigned long long*)(smem + 52224);
        int b = blk;
        const float* P = pos + (size_t)b * NPTS * 3;
        float* np = newpos + (size_t)b * SSAMP * 3;
        float px[16], py[16], pz[16], mind[16];
#pragma unroll
        for (int j = 0; j < 16; ++j) {
            int n = t + 256 * j;
            float X = P[n * 3 + 0], Y = P[n * 3 + 1], Z = P[n * 3 + 2];
            px[j] = X; py[j] = Y; pz[j] = Z;
            pxs[n] = X; pys[n] = Y; pzs[n] = Z;
            mind[j] = 3.402823466e+38f;
        }
        float cx = P[0], cy = P[1], cz = P[2];
        if (t == 0) { npb[0] = cx; npb[1] = cy; npb[2] = cz; }
        __syncthreads();
        for (int s = 1; s < SSAMP; ++s) {
            int p = s & 1;
            unsigned long long k[16];
#pragma unroll
            for (int j = 0; j < 16; ++j) {
                float dx = __fsub_rn(px[j], cx), dy = __fsub_rn(py[j], cy), dz = __fsub_rn(pz[j], cz);
                float d = __fadd_rn(__fadd_rn(__fmul_rn(dx, dx), __fmul_rn(dy, dy)), __fmul_rn(dz, dz));
                mind[j] = fminf(mind[j], d);
                k[j] = ((unsigned long long)__float_as_uint(mind[j]) << 32)
                     | (unsigned)~(unsigned)(t + 256 * j);
            }
#pragma unroll
            for (int st = 8; st > 0; st >>= 1)
#pragma unroll
                for (int j = 0; j < st; ++j) k[j] = umax64(k[j], k[j + st]);
            unsigned long long key = k[0];
            {
                unsigned long long a = __shfl_xor(key, 1, 64);
                unsigned long long b2 = __shfl_xor(key, 2, 64);
                unsigned long long c = __shfl_xor(key, 3, 64);
                key = umax64(umax64(key, a), umax64(b2, c));
                a = __shfl_xor(key, 4, 64);
                b2 = __shfl_xor(key, 8, 64);
                c = __shfl_xor(key, 12, 64);
                key = umax64(umax64(key, a), umax64(b2, c));
                a = __shfl_xor(key, 16, 64);
                b2 = __shfl_xor(key, 32, 64);
                c = __shfl_xor(key, 48, 64);
                key = umax64(umax64(key, a), umax64(b2, c));
            }
            if (lane == 0) rk[p * 4 + wave] = key;
            __syncthreads();
            unsigned long long k0 = rk[p * 4 + 0], k1 = rk[p * 4 + 1];
            unsigned long long k2 = rk[p * 4 + 2], k3 = rk[p * 4 + 3];
            unsigned long long bk = umax64(umax64(k0, k1), umax64(k2, k3));
            int nx = (int)(~(unsigned)(bk & 0xFFFFFFFFull));
            cx = pxs[nx]; cy = pys[nx]; cz = pzs[nx];
            if (t == 0) {
                npb[s * 3 + 0] = cx;
                npb[s * 3 + 1] = cy;
                npb[s * 3 + 2] = cz;
            }
            if ((s & 7) == 7) {
                if (t < 24) astore(&np[(s - 7) * 3 + t], npb[(s - 7) * 3 + t]);
                if (t == 0 && s >= 15)
                    __hip_atomic_store(&prog[b], s - 8, __ATOMIC_RELAXED, __HIP_MEMORY_SCOPE_AGENT);
            }
        }
        __syncthreads();
        if (t == 0)
            __hip_atomic_store(&prog[b], 255, __ATOMIC_RELAXED, __HIP_MEMORY_SCOPE_AGENT);
        return;
    }

    if (blk < 2056) {
        // ================= pointconv consumer (b,s) =================
        unsigned short* featl = (unsigned short*)smem;
        unsigned short* h2    = (unsigned short*)smem;
        unsigned short* h1    = (unsigned short*)(smem + 34816);
        float* mred = (float*)(smem + 34816);
        int*   vld  = (int*)(smem + 53248);
        int*   wl   = (int*)smem;
        int*   cnt  = (int*)(smem + 2048);
        float* wtb  = (float*)(smem + 26624);

        int cons = blk - 8;
        int s = cons >> 3, b = cons & 7;
        int bs = b * 256 + s;

        if (t == 0) spin_ge(&prog[b], s);
        __syncthreads();
        float q0 = aload(&newpos[(size_t)bs * 3 + 0]);
        float q1 = aload(&newpos[(size_t)bs * 3 + 1]);
        float q2 = aload(&newpos[(size_t)bs * 3 + 2]);

        const float* P = pos + (size_t)b * NPTS * 3;
        {
            int base = 0;
            for (int c = 0; c < 16 && base < KNBR; ++c) {
                int n = wave * 1024 + c * 64 + lane;
                float dx = __fsub_rn(P[n * 3 + 0], q0);
                float dy = __fsub_rn(P[n * 3 + 1], q1);
                float dz = __fsub_rn(P[n * 3 + 2], q2);
                float d2 = __fadd_rn(__fadd_rn(__fmul_rn(dx, dx), __fmul_rn(dy, dy)), __fmul_rn(dz, dz));
                bool in = (d2 <= 0.04f);
                unsigned long long mask = __ballot(in);
                if (in) {
                    int p = base + __popcll(mask & ((1ull << lane) - 1ull));
                    if (p < KNBR) wl[wave * 128 + p] = n;
                }
                base += __popcll(mask);
            }
            if (lane == 0) cnt[wave] = base < KNBR ? base : KNBR;
        }
        __syncthreads();
        {
            int c0 = cnt[0], c1 = cnt[1], c2 = cnt[2], c3 = cnt[3];
            if (t < 128) {
                int idx = -1, r = t;
                if (r < c0) idx = wl[r];
                else {
                    r -= c0;
                    if (r < c1) idx = wl[128 + r];
                    else {
                        r -= c1;
                        if (r < c2) idx = wl[256 + r];
                        else { r -= c2; if (r < c3) idx = wl[384 + r]; }
                    }
                }
                vld[t] = idx;
            }
            if (t < 192) wtb[t] = Wt[t];
            else wtb[t] = bt[t - 192];
        }
        __syncthreads();

        int vbits = 0;
#pragma unroll
        for (int i = 0; i < 2; ++i)
#pragma unroll
            for (int reg = 0; reg < 4; ++reg)
                if (vld[(2 * wave + i) * 16 + quad * 4 + reg] >= 0) vbits |= 1 << (i * 4 + reg);

        {
            int sr = t >> 1, sh = t & 1;
            int n = vld[sr];
            int ns = n < 0 ? 0 : n;
            const float* pp = pos + ((size_t)b * NPTS + ns) * 3;
            float p0 = pp[0], p1 = pp[1], p2 = pp[2];
            unsigned short* frow = &featl[sr * 104];
            u16x8 z8 = {0, 0, 0, 0, 0, 0, 0, 0};
            if (n >= 0) {
#pragma unroll
                for (int g = 0; g < 4; ++g) {
                    u16x8 v8;
#pragma unroll
                    for (int e = 0; e < 8; ++e) {
                        int c = sh * 32 + g * 8 + e;
                        float v = fmaf(p2, wtb[128 + c], fmaf(p1, wtb[64 + c], fmaf(p0, wtb[c], wtb[192 + c])));
                        v8[e] = (unsigned short)f2bf(lrelu01(v));
                    }
                    *(u16x8*)&frow[sh * 32 + g * 8] = v8;
                }
            } else {
#pragma unroll
                for (int g = 0; g < 4; ++g) *(u16x8*)&frow[sh * 32 + g * 8] = z8;
            }
            if (sh == 1) {
                u16x8 dv = z8;
                if (n >= 0) {
                    dv[0] = (unsigned short)f2bf(__fsub_rn(p0, q0));
                    dv[1] = (unsigned short)f2bf(__fsub_rn(p1, q1));
                    dv[2] = (unsigned short)f2bf(__fsub_rn(p2, q2));
                }
                *(u16x8*)&frow[64] = dv;
                *(u16x8*)&frow[72] = z8;
                *(u16x8*)&frow[80] = z8;
                *(u16x8*)&frow[88] = z8;
            }
        }
        __syncthreads();

        {
            f32x4 acc[2][4];
#pragma unroll
            for (int i = 0; i < 2; ++i)
#pragma unroll
                for (int nt = 0; nt < 4; ++nt) acc[i][nt] = (f32x4){0.f, 0.f, 0.f, 0.f};
#pragma unroll
            for (int ks = 0; ks < 3; ++ks) {
                bf16x8 afr[2];
#pragma unroll
                for (int i = 0; i < 2; ++i)
                    afr[i] = *(const bf16x8*)&featl[((2 * wave + i) * 16 + l16) * 104 + ks * 32 + quad * 8];
#pragma unroll
                for (int nt = 0; nt < 4; ++nt) {
                    bf16x8 bfr = *(const bf16x8*)(W1T + (nt * 16 + l16) * 96 + ks * 32 + quad * 8);
                    acc[0][nt] = MFMA16(afr[0], bfr, acc[0][nt]);
                    acc[1][nt] = MFMA16(afr[1], bfr, acc[1][nt]);
                }
            }
#pragma unroll
            for (int i = 0; i < 2; ++i)
#pragma unroll
                for (int nt = 0; nt < 4; ++nt) {
                    int col = nt * 16 + l16;
                    float bias = bc1[col];
#pragma unroll
                    for (int reg = 0; reg < 4; ++reg) {
                        int row = (2 * wave + i) * 16 + quad * 4 + reg;
                        h1[row * 72 + col] = f2bf(lrelu01(acc[i][nt][reg] + bias));
                    }
                }
        }
        __syncthreads();

        {
            f32x4 acc[2][8];
#pragma unroll
            for (int i = 0; i < 2; ++i)
#pragma unroll
                for (int nt = 0; nt < 8; ++nt) acc[i][nt] = (f32x4){0.f, 0.f, 0.f, 0.f};
#pragma unroll
            for (int ks = 0; ks < 2; ++ks) {
                bf16x8 afr[2];
#pragma unroll
                for (int i = 0; i < 2; ++i)
                    afr[i] = *(const bf16x8*)&h1[((2 * wave + i) * 16 + l16) * 72 + ks * 32 + quad * 8];
#pragma unroll
                for (int nt = 0; nt < 8; ++nt) {
                    bf16x8 bfr = *(const bf16x8*)(W2T + (nt * 16 + l16) * 64 + ks * 32 + quad * 8);
                    acc[0][nt] = MFMA16(afr[0], bfr, acc[0][nt]);
                    acc[1][nt] = MFMA16(afr[1], bfr, acc[1][nt]);
                }
            }
            __syncthreads();
#pragma unroll
            for (int i = 0; i < 2; ++i)
#pragma unroll
                for (int nt = 0; nt < 8; ++nt) {
                    int col = nt * 16 + l16;
                    float bias = bc2[col];
#pragma unroll
                    for (int reg = 0; reg < 4; ++reg) {
                        int row = (2 * wave + i) * 16 + quad * 4 + reg;
                        h2[row * 136 + col] = f2bf(lrelu01(acc[i][nt][reg] + bias));
                    }
                }
        }
        __syncthreads();

        for (int c3 = 0; c3 < 4; ++c3) {
            f32x4 acc[2][8];
#pragma unroll
            for (int i = 0; i < 2; ++i)
#pragma unroll
                for (int nt = 0; nt < 8; ++nt) acc[i][nt] = (f32x4){0.f, 0.f, 0.f, 0.f};
#pragma unroll
            for (int ks = 0; ks < 4; ++ks) {
                bf16x8 afr[2];
#pragma unroll
                for (int i = 0; i < 2; ++i)
                    afr[i] = *(const bf16x8*)&h2[((2 * wave + i) * 16 + l16) * 136 + ks * 32 + quad * 8];
#pragma unroll
                for (int nt = 0; nt < 8; ++nt) {
                    bf16x8 bfr = *(const bf16x8*)(W3T + ((size_t)((c3 * 8 + nt) * 16 + l16)) * 128 + ks * 32 + quad * 8);
                    acc[0][nt] = MFMA16(afr[0], bfr, acc[0][nt]);
                    acc[1][nt] = MFMA16(afr[1], bfr, acc[1][nt]);
                }
            }
#pragma unroll
            for (int nt = 0; nt < 8; ++nt) {
                float vmax = -3.402823466e+38f;
#pragma unroll
                for (int i = 0; i < 2; ++i)
#pragma unroll
                    for (int reg = 0; reg < 4; ++reg)
                        if (vbits & (1 << (i * 4 + reg))) vmax = fmaxf(vmax, acc[i][nt][reg]);
                vmax = fmaxf(vmax, __shfl_xor(vmax, 16));
                vmax = fmaxf(vmax, __shfl_xor(vmax, 32));
                if (lane < 16) mred[wave * 512 + (c3 * 8 + nt) * 16 + l16] = vmax;
            }
        }
        __syncthreads();
        unsigned short* erow = encin + (size_t)bs * 576;
        for (int c = t; c < 576; c += 256) {
            unsigned short v;
            if (c < 512) {
                float m4 = fmaxf(fmaxf(mred[c], mred[512 + c]), fmaxf(mred[1024 + c], mred[1536 + c]));
                v = f2bf(lrelu01(m4 + bc3[c]));
            } else if (c < 515) {
                v = f2bf(c == 512 ? q0 : (c == 513 ? q1 : q2));
            } else v = 0;
            erow[c] = v;
        }
        __syncthreads();
        if (t == 0) { __threadfence(); atomicAdd(&cnts[150 + (bs >> 7)], 1); }
        return;
    }

    if (blk < 2376) {
        // ================= e1 (2056..2120) / e2v (2120..2376) =================
        unsigned short* As = (unsigned short*)smem;
        bool is_e1 = blk < 2120;
        int rb, cb;
        const unsigned short* A;
        const unsigned short* BT;
        int Ka;
        if (is_e1) {
            int j = blk - 2056; rb = j >> 2; cb = j & 3; A = encin; BT = We1T; Ka = 576;
            if (t == 0) spin_ge(&cnts[150 + rb], 128);
        } else {
            int j = blk - 2120; rb = j >> 4; cb = j & 15; A = e1h; BT = We2T; Ka = 512;
            if (t == 0) spin_ge(&cnts[rb], 4);
        }
        __syncthreads();
        __threadfence();   // acquire bulk normal-store data (encin / e1h)
        int row0 = rb * 128, col0 = cb * 128;
        f32x4 acc[2][8];
#pragma unroll
        for (int i = 0; i < 2; ++i)
#pragma unroll
            for (int nt = 0; nt < 8; ++nt) acc[i][nt] = (f32x4){0.f, 0.f, 0.f, 0.f};
        int nk = Ka >> 6;
        int sr = t >> 1, sh = t & 1;
        const unsigned short* Arow = A + (size_t)(row0 + sr) * Ka + sh * 32;
        for (int ks = 0; ks < nk; ++ks) {
            u16x8 av[4];
#pragma unroll
            for (int j2 = 0; j2 < 4; ++j2) av[j2] = *(const u16x8*)(Arow + ks * 64 + j2 * 8);
            __syncthreads();
#pragma unroll
            for (int j2 = 0; j2 < 4; ++j2) *(u16x8*)&As[sr * 72 + sh * 32 + j2 * 8] = av[j2];
            __syncthreads();
#pragma unroll
            for (int ks2 = 0; ks2 < 2; ++ks2) {
                bf16x8 afr0 = *(const bf16x8*)&As[((2 * wave) * 16 + l16) * 72 + ks2 * 32 + quad * 8];
                bf16x8 afr1 = *(const bf16x8*)&As[((2 * wave + 1) * 16 + l16) * 72 + ks2 * 32 + quad * 8];
#pragma unroll
                for (int nt = 0; nt < 8; ++nt) {
                    bf16x8 bfr = *(const bf16x8*)(BT + (size_t)(col0 + nt * 16 + l16) * Ka + ks * 64 + ks2 * 32 + quad * 8);
                    acc[0][nt] = MFMA16(afr0, bfr, acc[0][nt]);
                    acc[1][nt] = MFMA16(afr1, bfr, acc[1][nt]);
                }
            }
        }
        if (is_e1) {
#pragma unroll
            for (int i = 0; i < 2; ++i)
#pragma unroll
                for (int nt = 0; nt < 8; ++nt) {
                    int col = col0 + nt * 16 + l16;
                    float bv = be1[col];
#pragma unroll
                    for (int reg = 0; reg < 4; ++reg) {
                        int row = row0 + (2 * wave + i) * 16 + quad * 4 + reg;
                        e1h[(size_t)row * 512 + col] = f2bf(lrelu01(acc[i][nt][reg] + bv));
                    }
                }
            __syncthreads();
            if (t == 0) { __threadfence(); atomicAdd(&cnts[rb], 1); }
        } else {
            int b = row0 >> 8;
#pragma unroll
            for (int nt = 0; nt < 8; ++nt) {
                int colp = col0 + nt * 16 + l16;
                int c2 = colp >> 1;
                int srcc = (colp & 1) ? 1024 + c2 : c2;
                float bv = be2[srcc];
                float num = 0.f, den = 0.f;
#pragma unroll
                for (int i = 0; i < 2; ++i)
#pragma unroll
                    for (int reg = 0; reg < 4; ++reg) {
                        float val = acc[i][nt][reg] + bv;
                        float par = __shfl_xor(val, 1, 64);
                        float d = expf(-0.5f * par);
                        num += val * d;
                        den += d;
                    }
                num += __shfl_xor(num, 16, 64); den += __shfl_xor(den, 16, 64);
                num += __shfl_xor(num, 32, 64); den += __shfl_xor(den, 32, 64);
                if (quad == 0 && !(l16 & 1)) {
                    atomicAdd(&zacc[((b << 10) + c2) * 2 + 0], num);
                    atomicAdd(&zacc[((b << 10) + c2) * 2 + 1], den);
                }
            }
            __syncthreads();
            if (t == 0) atomicAdd(&cnts[16], 1);
        }
        return;
    }

    // ================= ukern (2376..2392) =================
    {
        float* zt = (float*)smem;
        float* red = (float*)(smem + 32768);
        int j = blk - 2376;
        int dec = j >> 3, cb = j & 7;
        const float* W = dec ? Wf21 : Wf11;
        const float* bias = dec ? bf21 : bf11;
        float* u = dec ? u2 : u1;
        if (t == 0) spin_ge(&cnts[16], 256);
        __syncthreads();
#pragma unroll
        for (int i = 0; i < 32; ++i) {
            int o = t + i * 256;
            float num = aload(&zacc[o * 2 + 0]);
            float den = aload(&zacc[o * 2 + 1]);
            zt[(o & 1023) * 8 + (o >> 10)] = num / den;
        }
        __syncthreads();
        int c64 = t & 63, kc = t >> 6;
        int co = cb * 64 + c64;
        float acc[8];
#pragma unroll
        for (int r = 0; r < 8; ++r) acc[r] = 0.f;
        for (int i = 0; i < 256; ++i) {
            int ci = kc * 256 + i;
            float w = W[(size_t)ci * 512 + co];
            const float4* zp = (const float4*)&zt[ci * 8];
            float4 z0 = zp[0], z1 = zp[1];
            acc[0] = fmaf(z0.x, w, acc[0]); acc[1] = fmaf(z0.y, w, acc[1]);
            acc[2] = fmaf(z0.z, w, acc[2]); acc[3] = fmaf(z0.w, w, acc[3]);
            acc[4] = fmaf(z1.x, w, acc[4]); acc[5] = fmaf(z1.y, w, acc[5]);
            acc[6] = fmaf(z1.z, w, acc[6]); acc[7] = fmaf(z1.w, w, acc[7]);
        }
#pragma unroll
        for (int r = 0; r < 8; ++r) red[(kc * 64 + c64) * 8 + r] = acc[r];
        __syncthreads();
        if (kc == 0) {
#pragma unroll
            for (int r = 0; r < 8; ++r) {
                float v = red[(0 * 64 + c64) * 8 + r] + red[(1 * 64 + c64) * 8 + r]
                        + red[(2 * 64 + c64) * 8 + r] + red[(3 * 64 + c64) * 8 + r] + bias[co];
                astore(&u[r * 512 + co], v);
            }
        }
    }
}

// ---------------------------------------------------------------- tail: folds only, 1016 blocks.
// [0,508) ff1 (j,cc): NO spin (u1 ready by stream order) -> pts atomics + cnts[20+j];
// [508,1016) ff2 (j,cc): waits cnts[20+j]==4 -> out atomics.
__global__ void __launch_bounds__(256, 2) tail_kernel(
    int* __restrict__ cnts,
    const float* __restrict__ Wf11, const float* __restrict__ Wf21,
    const float* __restrict__ u1, const float* __restrict__ u2,
    const unsigned short* __restrict__ Wf12T, const float* __restrict__ bf12,
    const float* __restrict__ Wf13, const float* __restrict__ bf13,
    const unsigned short* __restrict__ Wf22T, const float* __restrict__ bf22,
    const float* __restrict__ Wf23, const float* __restrict__ bf23,
    float* __restrict__ pts, float* __restrict__ outv) {
    __shared__ __align__(16) unsigned char smem[40960];
    int blk = blockIdx.x, t = threadIdx.x;
    int wave = t >> 6, lane = t & 63, quad = lane >> 4, l16 = lane & 15;

    unsigned short* As = (unsigned short*)smem;          // 18432
    float* sW = (float*)(smem + 18432);                  // [3][512]
    float* sU = (float*)(smem + 24576);                  // [2][512]
    float* sP = (float*)(smem + 28672);                  // [128*3]
    float* sB = (float*)(smem + 30208);                  // [128]
    float* sRC = (float*)(smem + 30720);                 // [128][4]
    int dec = blk < 508 ? 0 : 1;
    int idx0 = blk - (dec ? 508 : 0);
    int j = idx0 >> 2, cc = idx0 & 3;
    const float* u = dec ? u2 : u1;
    const float* Wfold = dec ? Wf21 : Wf11;
    int nExtra = dec ? 3 : 2;
    const unsigned short* WT = dec ? Wf22T : Wf12T;
    const float* bmid = dec ? bf22 : bf12;
    const float* wout = dec ? Wf23 : Wf13;
    const float* bout = dec ? bf23 : bf13;
    float* ov = dec ? outv : pts;
    int row0 = j * 128, col0 = cc * 128;
    int b0 = row0 / 2025;

    // static preloads (before any spin)
    for (int idx = t; idx < 1536; idx += 256) {
        int r = idx >> 9, c = idx & 511;
        sW[r * 512 + c] = (r < nExtra) ? Wfold[(size_t)(1024 + r) * 512 + c] : 0.f;
    }
    for (int idx = t; idx < 384; idx += 256) sP[idx] = wout[col0 * 3 + idx];
    if (t < 128) sB[t] = bmid[col0 + t];
    for (int idx = t; idx < 1024; idx += 256) {
        int rb = idx >> 9;
        int bb = b0 + rb; if (bb > 7) bb = 7;
        sU[rb * 512 + (idx & 511)] = aload(&u[bb * 512 + (idx & 511)]);
    }
    if (dec == 0 && t < 128) {
        int rg = row0 + t; if (rg > 16199) rg = 16199;
        int b = rg / 2025, g = rg - b * 2025;
        int i = g / 45, jj = g - i * 45;
        sRC[t * 4 + 0] = (jj == 44) ? 0.3f : (float)(-0.3 + jj * (0.6 / 44.0));
        sRC[t * 4 + 1] = (i == 44) ? 0.3f : (float)(-0.3 + i * (0.6 / 44.0));
        sRC[t * 4 + 2] = 0.f;
        sRC[t * 4 + 3] = __int_as_float(b - b0);
    }

    if (dec) {
        if (t == 0) spin_ge(&cnts[20 + j], 4);
        __syncthreads();
        if (t < 128) {
            int rg = row0 + t; if (rg > 16199) rg = 16199;
            int b = rg / 2025;
            sRC[t * 4 + 0] = aload(&pts[rg * 3 + 0]);
            sRC[t * 4 + 1] = aload(&pts[rg * 3 + 1]);
            sRC[t * 4 + 2] = aload(&pts[rg * 3 + 2]);
            sRC[t * 4 + 3] = __int_as_float(b - b0);
        }
    }
    __syncthreads();

    float proj[2][4][3];
#pragma unroll
    for (int i = 0; i < 2; ++i)
#pragma unroll
        for (int r = 0; r < 4; ++r) { proj[i][r][0] = 0.f; proj[i][r][1] = 0.f; proj[i][r][2] = 0.f; }

    int sr = t >> 1, sh = t & 1;
    float4 rc = *(const float4*)&sRC[sr * 4];
    int ubi = __float_as_int(rc.w);
    const float* up = sU + ubi * 512;
    f32x4 acc[2][8];
#pragma unroll
    for (int i = 0; i < 2; ++i)
#pragma unroll
        for (int nt = 0; nt < 8; ++nt) acc[i][nt] = (f32x4){0.f, 0.f, 0.f, 0.f};
    for (int ks = 0; ks < 8; ++ks) {
        __syncthreads();
        {
            int cbase = ks * 64 + sh * 32;
            const float4* w0p = (const float4*)&sW[cbase];
            const float4* w1p = (const float4*)&sW[512 + cbase];
            const float4* w2p = (const float4*)&sW[1024 + cbase];
            const float4* uup = (const float4*)&up[cbase];
#pragma unroll
            for (int g4 = 0; g4 < 8; ++g4) {
                float4 w0 = w0p[g4], w1 = w1p[g4], w2 = w2p[g4], uu = uup[g4];
                float v0 = fmaf(rc.z, w2.x, fmaf(rc.y, w1.x, fmaf(rc.x, w0.x, uu.x)));
                float v1 = fmaf(rc.z, w2.y, fmaf(rc.y, w1.y, fmaf(rc.x, w0.y, uu.y)));
                float v2 = fmaf(rc.z, w2.z, fmaf(rc.y, w1.z, fmaf(rc.x, w0.z, uu.z)));
                float v3 = fmaf(rc.z, w2.w, fmaf(rc.y, w1.w, fmaf(rc.x, w0.w, uu.w)));
                uint2 pk;
                pk.x = (unsigned)f2bf(fmaxf(v0, 0.f)) | ((unsigned)f2bf(fmaxf(v1, 0.f)) << 16);
                pk.y = (unsigned)f2bf(fmaxf(v2, 0.f)) | ((unsigned)f2bf(fmaxf(v3, 0.f)) << 16);
                *(uint2*)&As[sr * 72 + sh * 32 + g4 * 4] = pk;
            }
        }
        __syncthreads();
#pragma unroll
        for (int ks2 = 0; ks2 < 2; ++ks2) {
            bf16x8 afr0 = *(const bf16x8*)&As[((2 * wave) * 16 + l16) * 72 + ks2 * 32 + quad * 8];
            bf16x8 afr1 = *(const bf16x8*)&As[((2 * wave + 1) * 16 + l16) * 72 + ks2 * 32 + quad * 8];
#pragma unroll
            for (int nt = 0; nt < 8; ++nt) {
                bf16x8 bfr = *(const bf16x8*)(WT + (size_t)(col0 + nt * 16 + l16) * 512 + ks * 64 + ks2 * 32 + quad * 8);
                acc[0][nt] = MFMA16(afr0, bfr, acc[0][nt]);
                acc[1][nt] = MFMA16(afr1, bfr, acc[1][nt]);
            }
        }
    }
#pragma unroll
    for (int i = 0; i < 2; ++i)
#pragma unroll
        for (int nt = 0; nt < 8; ++nt) {
            int lc = nt * 16 + l16;
            float bv = sB[lc];
            float w0 = sP[lc * 3 + 0], w1 = sP[lc * 3 + 1], w2 = sP[lc * 3 + 2];
#pragma unroll
            for (int reg = 0; reg < 4; ++reg) {
                float h = fmaxf(acc[i][nt][reg] + bv, 0.f);
                proj[i][reg][0] = fmaf(h, w0, proj[i][reg][0]);
                proj[i][reg][1] = fmaf(h, w1, proj[i][reg][1]);
                proj[i][reg][2] = fmaf(h, w2, proj[i][reg][2]);
            }
        }
    float o0 = (cc == 0) ? bout[0] : 0.f;
    float o1 = (cc == 0) ? bout[1] : 0.f;
    float o2 = (cc == 0) ? bout[2] : 0.f;
#pragma unroll
    for (int i = 0; i < 2; ++i)
#pragma unroll
        for (int reg = 0; reg < 4; ++reg) {
            float p0 = proj[i][reg][0], p1 = proj[i][reg][1], p2 = proj[i][reg][2];
#pragma unroll
            for (int m = 1; m < 16; m <<= 1) {
                p0 += __shfl_xor(p0, m, 64);
                p1 += __shfl_xor(p1, m, 64);
                p2 += __shfl_xor(p2, m, 64);
            }
            if (l16 == 0) {
                int row = row0 + (2 * wave + i) * 16 + quad * 4 + reg;
                if (row < 16200) {
                    atomicAdd(&ov[row * 3 + 0], p0 + o0);
                    atomicAdd(&ov[row * 3 + 1], p1 + o1);
                    atomicAdd(&ov[row * 3 + 2], p2 + o2);
                }
            }
        }
    if (dec == 0) {
        __syncthreads();
        if (t == 0) atomicAdd(&cnts[20 + j], 1);
    }
}

extern "C" void kernel_launch(void* const* d_in, const int* in_sizes, int n_in,
                              void* d_out, int out_size, void* d_ws, size_t ws_size,
                              hipStream_t stream) {
    const float* pos  = (const float*)d_in[0];
    const float* Wt   = (const float*)d_in[1];
    const float* bt   = (const float*)d_in[2];
    const float* Wc1  = (const float*)d_in[3];
    const float* bc1  = (const float*)d_in[4];
    const float* Wc2  = (const float*)d_in[5];
    const float* bc2  = (const float*)d_in[6];
    const float* Wc3  = (const float*)d_in[7];
    const float* bc3  = (const float*)d_in[8];
    const float* We1  = (const float*)d_in[9];
    const float* be1  = (const float*)d_in[10];
    const float* We2  = (const float*)d_in[11];
    const float* be2  = (const float*)d_in[12];
    const float* Wf11 = (const float*)d_in[13];
    const float* bf11 = (const float*)d_in[14];
    const float* Wf12 = (const float*)d_in[15];
    const float* bf12 = (const float*)d_in[16];
    const float* Wf13 = (const float*)d_in[17];
    const float* bf13 = (const float*)d_in[18];
    const float* Wf21 = (const float*)d_in[19];
    const float* bf21 = (const float*)d_in[20];
    const float* Wf22 = (const float*)d_in[21];
    const float* bf22 = (const float*)d_in[22];
    const float* Wf23 = (const float*)d_in[23];
    const float* bf23 = (const float*)d_in[24];
    float* out = (float*)d_out;

    float* wsf = (float*)d_ws;
    size_t off = 0;
    unsigned short* encinh= (unsigned short*)(wsf + off); off += 589824;   // [2048][576] bf16
    unsigned short* e1h   = (unsigned short*)(wsf + off); off += 524288;   // [2048][512] bf16
    float* zacc = wsf + off; off += 16384;     // [8][1024][2]
    float* u1   = wsf + off; off += 4096;
    float* u2   = wsf + off; off += 4096;
    float* pts  = wsf + off; off += 48600;     // [16200][3] (atomic-accumulated)
    float* newp = wsf + off; off += 6144;      // [B,S,3]
    int*   prog = (int*)(wsf + off); off += 16;
    int*   cnts = (int*)(wsf + off); off += 256;
    unsigned short* W1T   = (unsigned short*)(wsf + off); off += 3072;
    unsigned short* W2T   = (unsigned short*)(wsf + off); off += 4096;
    unsigned short* W3T   = (unsigned short*)(wsf + off); off += 32768;
    unsigned short* We1T  = (unsigned short*)(wsf + off); off += 147456;
    unsigned short* We2T  = (unsigned short*)(wsf + off); off += 524288;
    unsigned short* Wf12T = (unsigned short*)(wsf + off); off += 131072;
    unsigned short* Wf22T = (unsigned short*)(wsf + off); off += 131072;

    hipMemsetAsync(prog, 0xFF, 64, stream);
    hipMemsetAsync(cnts, 0x00, 1024, stream);
    hipMemsetAsync(zacc, 0x00, 16384 * 4, stream);
    hipMemsetAsync(pts, 0x00, 48600 * 4, stream);
    hipMemsetAsync(out, 0x00, (size_t)out_size * 4, stream);
    preconv_kernel<<<7608, 256, 0, stream>>>(Wc1, Wc2, Wc3, We1, We2, Wf12, Wf22,
                                             W1T, W2T, W3T, We1T, We2T, Wf12T, Wf22T);
    stage1_kernel<<<2392, 256, 0, stream>>>(pos, newp, prog, cnts, Wt, bt, W1T, W2T, W3T,
                                            bc1, bc2, bc3, encinh,
                                            We1T, be1, e1h, We2T, be2, zacc,
                                            Wf11, bf11, Wf21, bf21, u1, u2);
    tail_kernel<<<1016, 256, 0, stream>>>(cnts, Wf11, Wf21, u1, u2,
                                          Wf12T, bf12, Wf13, bf13,
                                          Wf22T, bf22, Wf23, bf23, pts, out);
}